// Round 5
// baseline (1718.696 us; speedup 1.0000x reference)
//
#include <hip/hip_runtime.h>
#include <hip/hip_bf16.h>

typedef __hip_bfloat16 bf16;
typedef unsigned short u16;
typedef unsigned int u32;

static __device__ __forceinline__ float b2f(bf16 v) { return __bfloat162float(v); }

#define TILE 8192   // edges per partition block

// ---------------- dtype detection ----------------
__global__ void k_detect(const u16* __restrict__ xraw, int* __restrict__ flag) {
    __shared__ int s;
    if (threadIdx.x == 0) s = 0;
    __syncthreads();
    u16 u = xraw[threadIdx.x];
    int e = (u >> 7) & 0xFF;
    if (e >= 0x8F) atomicAdd(&s, 1);
    __syncthreads();
    if (threadIdx.x == 0) flag[0] = (s > 0) ? 1 : 0;
}

__global__ void k_zero(int* __restrict__ a, int n) {
    int i = blockIdx.x * blockDim.x + threadIdx.x;
    if (i < n) a[i] = 0;
}

// ---------------- pass A: partition edges into dst-range buckets ----------------
// pairs[bucket*cap + slot] = (bucket_local_dst << 21) | src
__global__ void k_partition(const int* __restrict__ src, const int* __restrict__ dst,
                            int E, int bits, int cap,
                            int* __restrict__ gcursor, u32* __restrict__ pairs) {
    __shared__ int hist[512];
    __shared__ int cur[512];
    int t = threadIdx.x;
    for (int i = t; i < 512; i += 256) hist[i] = 0;
    __syncthreads();
    int e0 = blockIdx.x * TILE;
    int e1 = min(e0 + TILE, E);
    for (int e = e0 + t; e < e1; e += 256)
        atomicAdd(&hist[dst[e] >> bits], 1);
    __syncthreads();
    for (int b = t; b < 512; b += 256) {
        int h = hist[b];
        cur[b] = h ? atomicAdd(&gcursor[b], h) : 0;
    }
    __syncthreads();
    u32 mask = (1u << bits) - 1u;
    for (int e = e0 + t; e < e1; e += 256) {
        int d = dst[e];
        int b = d >> bits;
        int pos = atomicAdd(&cur[b], 1);
        pairs[(size_t)b * cap + pos] = (((u32)d & mask) << 21) | (u32)src[e];
    }
}

// ---------------- pass B1: per-bucket histogram -> cnt ----------------
__global__ void k_bucket_count(const u32* __restrict__ pairs, const int* __restrict__ gcursor,
                               int cap, int bits, int N, int* __restrict__ cnt) {
    __shared__ int hist[2048];
    int b = blockIdx.x, t = threadIdx.x;
    int range = 1 << bits;
    for (int i = t; i < range; i += 256) hist[i] = 0;
    __syncthreads();
    int n = gcursor[b];
    const u32* p = pairs + (size_t)b * cap;
    for (int i = t; i < n; i += 256)
        atomicAdd(&hist[p[i] >> 21], 1);
    __syncthreads();
    int base = b << bits;
    for (int i = t; i < range; i += 256) {
        int v = base + i;
        if (v < N) cnt[v] = hist[i];
    }
}

// ---------------- global exclusive scan of cnt -> rowptr (+dis) ----------------
__global__ void k_scan_partial(const int* __restrict__ cnt, int* __restrict__ partial, int n) {
    __shared__ int lds[256];
    int t = threadIdx.x;
    int base = blockIdx.x * 1024 + t * 4;
    int s = 0;
    #pragma unroll
    for (int k = 0; k < 4; k++) { int i = base + k; if (i < n) s += cnt[i]; }
    lds[t] = s; __syncthreads();
    for (int off = 128; off > 0; off >>= 1) {
        if (t < off) lds[t] += lds[t + off];
        __syncthreads();
    }
    if (t == 0) partial[blockIdx.x] = lds[0];
}

__global__ void k_scan_block(int* __restrict__ partial, int m) {
    __shared__ int lds[1024];
    int t = threadIdx.x;
    int v = (t < m) ? partial[t] : 0;
    lds[t] = v; __syncthreads();
    for (int off = 1; off < 1024; off <<= 1) {
        int tmp = (t >= off) ? lds[t - off] : 0;
        __syncthreads();
        lds[t] += tmp;
        __syncthreads();
    }
    if (t < m) partial[t] = lds[t] - v;  // exclusive
}

__global__ void k_scan_final(const int* __restrict__ cnt, const int* __restrict__ partial,
                             int* __restrict__ rowptr, float* __restrict__ dis, int n) {
    __shared__ int lds[256];
    int t = threadIdx.x;
    int base = blockIdx.x * 1024 + t * 4;
    int a[4]; int s = 0;
    #pragma unroll
    for (int k = 0; k < 4; k++) { int i = base + k; a[k] = (i < n) ? cnt[i] : 0; s += a[k]; }
    lds[t] = s; __syncthreads();
    for (int off = 1; off < 256; off <<= 1) {
        int tmp = (t >= off) ? lds[t - off] : 0;
        __syncthreads();
        lds[t] += tmp;
        __syncthreads();
    }
    int run = partial[blockIdx.x] + lds[t] - s;
    #pragma unroll
    for (int k = 0; k < 4; k++) {
        int i = base + k;
        if (i < n) {
            rowptr[i] = run;
            dis[i] = rsqrtf((float)(a[k] + 1));
            run += a[k];
        }
    }
}

// ---------------- pass B2: per-bucket scatter into contiguous csr span ----------------
// csr[pos] = ((dst & nvmask) << 21) | src   (nvmask = gather NV-1, NV pow2,
// gather blocks are NV-aligned so dst&(NV-1) == dst - v0 of the owning block)
__global__ void k_bucket_fill(const u32* __restrict__ pairs, const int* __restrict__ gcursor,
                              int cap, int bits, int N, u32 nvmask,
                              const int* __restrict__ rowptr, int* __restrict__ csr) {
    __shared__ int cur[2048];
    int b = blockIdx.x, t = threadIdx.x;
    int range = 1 << bits;
    int base = b << bits;
    for (int i = t; i < range; i += 256) {
        int v = base + i;
        cur[i] = (v < N) ? rowptr[v] : 0;
    }
    __syncthreads();
    int n = gcursor[b];
    const u32* p = pairs + (size_t)b * cap;
    for (int i = t; i < n; i += 256) {
        u32 u = p[i];
        u32 dl = u >> 21;
        u32 d = (u32)base + dl;
        int pos = atomicAdd(&cur[dl], 1);
        csr[pos] = (int)(((d & nvmask) << 21) | (u & 0x1FFFFFu));
    }
}

// ---------------- per-node matmul, pre-scaled by dis[v] ----------------
template <int FIN, int FOUT, bool EXT>
__global__ void k_matmul(const void* __restrict__ xin, const int* __restrict__ gidx,
                         const bf16* __restrict__ actin,
                         const void* __restrict__ W, const float* __restrict__ dis,
                         bf16* __restrict__ g, const int* __restrict__ flag, int n) {
    __shared__ float Ws[FIN * FOUT];
    const int f32m = flag[0];
    for (int i = threadIdx.x; i < FIN * FOUT; i += blockDim.x)
        Ws[i] = f32m ? ((const float*)W)[i] : b2f(((const bf16*)W)[i]);
    __syncthreads();
    int v = blockIdx.x * blockDim.x + threadIdx.x;
    if (v >= n) return;

    float x[FIN];
    if (EXT) {
        if (f32m) {
            const float* p = (const float*)xin;
            #pragma unroll
            for (int k = 0; k < FIN; k++) x[k] = p[(size_t)v * FIN + k];
        } else {
            const bf16* p = (const bf16*)xin;
            #pragma unroll
            for (int k = 0; k < FIN; k++) x[k] = b2f(p[(size_t)v * FIN + k]);
        }
    } else {
        int row = gidx[v];
        #pragma unroll
        for (int k = 0; k < FIN; k++) x[k] = b2f(actin[(size_t)row * FIN + k]);
    }

    float y[FOUT];
    #pragma unroll
    for (int f = 0; f < FOUT; f++) y[f] = 0.f;
    #pragma unroll
    for (int k = 0; k < FIN; k++) {
        float xk = x[k];
        #pragma unroll
        for (int f = 0; f < FOUT; f++) y[f] = fmaf(xk, Ws[k * FOUT + f], y[f]);
    }

    float dv = dis[v];
    #pragma unroll
    for (int f = 0; f < FOUT; f++)
        g[(size_t)v * FOUT + f] = __float2bfloat16(dv * y[f]);
}

// ---------------- edge-parallel gather + finalize ----------------
// Block owns nodes [v0, v0+NV). LDS f32 acc initialized with self rows of g,
// then contiguous csr span processed by lane-groups (GSZ lanes per edge):
// all g[u] loads independent -> high MLP. Finalize fused.
template <int FOUT, int NV, int GSZ>
__global__ void k_gather2(const bf16* __restrict__ g, const int* __restrict__ rowptr,
                          const int* __restrict__ csr, const float* __restrict__ dis,
                          const void* __restrict__ bias, bf16* __restrict__ act,
                          const int* __restrict__ flag, int N, int E) {
    __shared__ float acc[NV * FOUT];
    int t = threadIdx.x;
    int v0 = blockIdx.x * NV;
    int nv = min(NV, N - v0);
    int lim = nv * FOUT;
    // self-init (coalesced contiguous)
    for (int i = t; i < lim; i += 256)
        acc[i] = b2f(g[(size_t)v0 * FOUT + i]);
    __syncthreads();
    int R0 = rowptr[v0];
    int R1 = (v0 + NV >= N) ? E : rowptr[v0 + NV];
    const int ngroups = 256 / GSZ;
    int gid = t / GSZ;
    int f = t % GSZ;
    for (int e = R0 + gid; e < R1; e += ngroups) {
        u32 entry = (u32)csr[e];
        int dl = entry >> 21;
        int u = (int)(entry & 0x1FFFFFu);
        if (f < FOUT)
            atomicAdd(&acc[dl * FOUT + f], b2f(g[(size_t)u * FOUT + f]));
    }
    __syncthreads();
    const int f32m = flag[0];
    for (int i = t; i < lim; i += 256) {
        int vl = i / FOUT;
        int ff = i - vl * FOUT;
        float bf = f32m ? ((const float*)bias)[ff] : b2f(((const bf16*)bias)[ff]);
        float val = fmaf(dis[v0 + vl], acc[i], bf);
        act[(size_t)v0 * FOUT + i] = __float2bfloat16(val > 0.f ? val : 0.f);
    }
}

// ---------------- final unpool gather -> out (dtype per flag) ----------------
__global__ void k_gather_out(const bf16* __restrict__ act, const int* __restrict__ idx,
                             void* __restrict__ out, const int* __restrict__ flag, int n) {
    int u = blockIdx.x * blockDim.x + threadIdx.x;
    if (u >= n) return;
    size_t r = (size_t)idx[u];
    float v0 = b2f(act[3 * r + 0]);
    float v1 = b2f(act[3 * r + 1]);
    float v2 = b2f(act[3 * r + 2]);
    if (flag[0]) {
        float* o = (float*)out;
        o[3 * (size_t)u + 0] = v0; o[3 * (size_t)u + 1] = v1; o[3 * (size_t)u + 2] = v2;
    } else {
        bf16* o = (bf16*)out;
        o[3 * (size_t)u + 0] = __float2bfloat16(v0);
        o[3 * (size_t)u + 1] = __float2bfloat16(v1);
        o[3 * (size_t)u + 2] = __float2bfloat16(v2);
    }
}

// ---------------- host-side stage driver ----------------
struct Ws {
    int* flag; float* dis; int* cnt; int* rowptr; int* partial; int* gcursor;
    int* csr; u32* pairs; bf16* g; /* g aliases pairs */ bf16* act;
};

static inline int cdiv(long long a, long long b) { return (int)((a + b - 1) / b); }

static inline int range_bits_for(int N) {
    int bits = 8;
    while (cdiv(N, 1 << bits) > 512) bits++;
    return bits;
}

template <int FIN, int FOUT, bool EXT, int NV, int GSZ>
static void run_stage(const void* xin, const int* gidx, const bf16* actin,
                      const void* W, const void* bias,
                      const int* src, const int* dst, int E, int N,
                      const Ws& w, hipStream_t stream) {
    const int B = 256;
    int bits = range_bits_for(N);
    int nb = cdiv(N, 1 << bits);
    int cap = E / nb + E / (4 * nb) + 256;
    int nScanBlocks = cdiv(N, 1024);

    k_zero<<<1, 512, 0, stream>>>(w.gcursor, 512);
    k_partition<<<cdiv(E, TILE), B, 0, stream>>>(src, dst, E, bits, cap, w.gcursor, w.pairs);
    k_bucket_count<<<nb, B, 0, stream>>>(w.pairs, w.gcursor, cap, bits, N, w.cnt);
    k_scan_partial<<<nScanBlocks, B, 0, stream>>>(w.cnt, w.partial, N);
    k_scan_block<<<1, 1024, 0, stream>>>(w.partial, nScanBlocks);
    k_scan_final<<<nScanBlocks, B, 0, stream>>>(w.cnt, w.partial, w.rowptr, w.dis, N);
    k_bucket_fill<<<nb, B, 0, stream>>>(w.pairs, w.gcursor, cap, bits, N, (u32)(NV - 1), w.rowptr, w.csr);
    // g aliases pairs: pairs dead after k_bucket_fill
    k_matmul<FIN, FOUT, EXT><<<cdiv(N, B), B, 0, stream>>>(xin, gidx, actin, W, w.dis, w.g, w.flag, N);
    k_gather2<FOUT, NV, GSZ><<<cdiv(N, NV), B, 0, stream>>>(
        w.g, w.rowptr, w.csr, w.dis, bias, w.act, w.flag, N, E);
}

extern "C" void kernel_launch(void* const* d_in, const int* in_sizes, int n_in,
                              void* d_out, int out_size, void* d_ws, size_t ws_size,
                              hipStream_t stream) {
    const void* x  = d_in[0];
    const void* W1 = d_in[1]; const void* b1 = d_in[2];
    const void* W2 = d_in[3]; const void* b2 = d_in[4];
    const void* W3 = d_in[5]; const void* b3 = d_in[6];
    const void* W4 = d_in[7]; const void* b4 = d_in[8];
    const int* e0  = (const int*)d_in[9];
    const int* up1 = (const int*)d_in[10];
    const int* e1  = (const int*)d_in[11];
    const int* up2 = (const int*)d_in[12];
    const int* e2  = (const int*)d_in[13];
    const int* up3 = (const int*)d_in[14];
    const int* e3  = (const int*)d_in[15];
    const int* up4 = (const int*)d_in[16];

    const int N0 = in_sizes[0] / 3;
    const int N1 = in_sizes[10];
    const int N2 = in_sizes[12];
    const int N3 = in_sizes[14];
    const int N4 = in_sizes[16];
    const int E0 = in_sizes[9] / 2, E1 = in_sizes[11] / 2;
    const int E2 = in_sizes[13] / 2, E3 = in_sizes[15] / 2;

    // capacities
    size_t CAP = (size_t)N0 * 32;
    if ((size_t)N1 * 64 > CAP) CAP = (size_t)N1 * 64;
    if ((size_t)N2 * 32 > CAP) CAP = (size_t)N2 * 32;
    if ((size_t)N3 * 3  > CAP) CAP = (size_t)N3 * 3;
    size_t maxN = (size_t)(N3 > N2 ? N3 : N2);
    if ((size_t)N1 > maxN) maxN = N1;
    if ((size_t)N0 > maxN) maxN = N0;
    size_t maxE = (size_t)(E3 > E2 ? E3 : E2);
    if ((size_t)E1 > maxE) maxE = E1;
    if ((size_t)E0 > maxE) maxE = E0;
    size_t maxN4 = (maxN + 3) & ~(size_t)3;

    // max pairs capacity over stages
    size_t maxPairs = 0;
    {
        int Ns[4] = {N0, N1, N2, N3};
        int Es[4] = {E0, E1, E2, E3};
        for (int s = 0; s < 4; s++) {
            int bits = range_bits_for(Ns[s]);
            int nb = cdiv(Ns[s], 1 << bits);
            size_t cap = (size_t)(Es[s] / nb + Es[s] / (4 * nb) + 256);
            size_t tot = cap * (size_t)nb;
            if (tot > maxPairs) maxPairs = tot;
        }
    }

    // workspace layout (~80 MB): pairs/g share a union region
    size_t uBytes = maxPairs * 4;
    if (CAP * 2 > uBytes) uBytes = CAP * 2;
    uBytes = (uBytes + 255) & ~(size_t)255;

    char* p = (char*)d_ws;
    Ws w;
    w.flag    = (int*)p;            p += 256;
    w.dis     = (float*)p;          p += maxN4 * 4;
    w.cnt     = (int*)p;            p += maxN4 * 4;
    w.rowptr  = (int*)p;            p += maxN4 * 4;
    w.partial = (int*)p;            p += 4096 * 4;
    w.gcursor = (int*)p;            p += 1024 * 4;
    w.csr     = (int*)p;            p += ((maxE + 3) & ~(size_t)3) * 4;
    w.pairs   = (u32*)p;
    w.g       = (bf16*)p;           p += uBytes;
    w.act     = (bf16*)p;           // CAP bf16

    const int B = 256;

    k_detect<<<1, 256, 0, stream>>>((const u16*)x, w.flag);

    // stage 1: x @ W1 -> 32, graph e0 (N0), gather NV=128 (16KB LDS)
    run_stage<3, 32, true, 128, 32>(x, nullptr, nullptr, W1, b1, e0, e0 + E0, E0, N0, w, stream);
    // stage 2: act1[up1] @ W2 -> 64, graph e1 (N1), NV=64 (16KB)
    run_stage<32, 64, false, 64, 64>(nullptr, up1, w.act, W2, b2, e1, e1 + E1, E1, N1, w, stream);
    // stage 3: act2[up2] @ W3 -> 32, graph e2 (N2), NV=128 (16KB)
    run_stage<64, 32, false, 128, 32>(nullptr, up2, w.act, W3, b3, e2, e2 + E2, E2, N2, w, stream);
    // stage 4: act3[up3] @ W4 -> 3, graph e3 (N3), NV=512 (6KB), 4-lane groups
    run_stage<32, 3, false, 512, 4>(nullptr, up3, w.act, W4, b4, e3, e3 + E3, E3, N3, w, stream);

    // final unpool
    k_gather_out<<<cdiv(N4, B), B, 0, stream>>>(w.act, up4, d_out, w.flag, N4);
}

// Round 6
// 857.090 us; speedup vs baseline: 2.0053x; 2.0053x over previous
//
#include <hip/hip_runtime.h>
#include <hip/hip_bf16.h>

typedef __hip_bfloat16 bf16;
typedef unsigned short u16;
typedef unsigned int u32;

static __device__ __forceinline__ float b2f(bf16 v) { return __bfloat162float(v); }

#define TILE 8192   // edges per partition block

// ---------------- dtype detection ----------------
__global__ void k_detect(const u16* __restrict__ xraw, int* __restrict__ flag) {
    __shared__ int s;
    if (threadIdx.x == 0) s = 0;
    __syncthreads();
    u16 u = xraw[threadIdx.x];
    int e = (u >> 7) & 0xFF;
    if (e >= 0x8F) atomicAdd(&s, 1);
    __syncthreads();
    if (threadIdx.x == 0) flag[0] = (s > 0) ? 1 : 0;
}

__global__ void k_zero(int* __restrict__ a, int n) {
    int i = blockIdx.x * blockDim.x + threadIdx.x;
    if (i < n) a[i] = 0;
}

// ---------------- pass A: partition edges into dst-range buckets ----------------
// pairs[bucket*cap + slot] = (bucket_local_dst << 21) | src
__global__ void k_partition(const int* __restrict__ src, const int* __restrict__ dst,
                            int E, int bits, int cap,
                            int* __restrict__ gcursor, u32* __restrict__ pairs) {
    __shared__ int hist[512];
    __shared__ int cur[512];
    int t = threadIdx.x;
    for (int i = t; i < 512; i += 256) hist[i] = 0;
    __syncthreads();
    int e0 = blockIdx.x * TILE;
    int e1 = min(e0 + TILE, E);
    for (int e = e0 + t; e < e1; e += 256)
        atomicAdd(&hist[dst[e] >> bits], 1);
    __syncthreads();
    for (int b = t; b < 512; b += 256) {
        int h = hist[b];
        cur[b] = h ? atomicAdd(&gcursor[b], h) : 0;
    }
    __syncthreads();
    u32 mask = (1u << bits) - 1u;
    for (int e = e0 + t; e < e1; e += 256) {
        int d = dst[e];
        int b = d >> bits;
        int pos = atomicAdd(&cur[b], 1);
        pairs[(size_t)b * cap + pos] = (((u32)d & mask) << 21) | (u32)src[e];
    }
}

// ---------------- pass B1: per-bucket histogram -> cnt ----------------
__global__ void k_bucket_count(const u32* __restrict__ pairs, const int* __restrict__ gcursor,
                               int cap, int bits, int N, int* __restrict__ cnt) {
    __shared__ int hist[2048];
    int b = blockIdx.x, t = threadIdx.x;
    int range = 1 << bits;
    for (int i = t; i < range; i += 256) hist[i] = 0;
    __syncthreads();
    int n = gcursor[b];
    const u32* p = pairs + (size_t)b * cap;
    for (int i = t; i < n; i += 256)
        atomicAdd(&hist[p[i] >> 21], 1);
    __syncthreads();
    int base = b << bits;
    for (int i = t; i < range; i += 256) {
        int v = base + i;
        if (v < N) cnt[v] = hist[i];
    }
}

// ---------------- global exclusive scan of cnt -> rowptr (+dis) ----------------
__global__ void k_scan_partial(const int* __restrict__ cnt, int* __restrict__ partial, int n) {
    __shared__ int lds[256];
    int t = threadIdx.x;
    int base = blockIdx.x * 1024 + t * 4;
    int s = 0;
    #pragma unroll
    for (int k = 0; k < 4; k++) { int i = base + k; if (i < n) s += cnt[i]; }
    lds[t] = s; __syncthreads();
    for (int off = 128; off > 0; off >>= 1) {
        if (t < off) lds[t] += lds[t + off];
        __syncthreads();
    }
    if (t == 0) partial[blockIdx.x] = lds[0];
}

__global__ void k_scan_block(int* __restrict__ partial, int m) {
    __shared__ int lds[1024];
    int t = threadIdx.x;
    int v = (t < m) ? partial[t] : 0;
    lds[t] = v; __syncthreads();
    for (int off = 1; off < 1024; off <<= 1) {
        int tmp = (t >= off) ? lds[t - off] : 0;
        __syncthreads();
        lds[t] += tmp;
        __syncthreads();
    }
    if (t < m) partial[t] = lds[t] - v;  // exclusive
}

__global__ void k_scan_final(const int* __restrict__ cnt, const int* __restrict__ partial,
                             int* __restrict__ rowptr, float* __restrict__ dis, int n) {
    __shared__ int lds[256];
    int t = threadIdx.x;
    int base = blockIdx.x * 1024 + t * 4;
    int a[4]; int s = 0;
    #pragma unroll
    for (int k = 0; k < 4; k++) { int i = base + k; a[k] = (i < n) ? cnt[i] : 0; s += a[k]; }
    lds[t] = s; __syncthreads();
    for (int off = 1; off < 256; off <<= 1) {
        int tmp = (t >= off) ? lds[t - off] : 0;
        __syncthreads();
        lds[t] += tmp;
        __syncthreads();
    }
    int run = partial[blockIdx.x] + lds[t] - s;
    #pragma unroll
    for (int k = 0; k < 4; k++) {
        int i = base + k;
        if (i < n) {
            rowptr[i] = run;
            dis[i] = rsqrtf((float)(a[k] + 1));
            run += a[k];
        }
    }
}

// ---------------- pass B2: per-bucket scatter into contiguous csr span ----------------
__global__ void k_bucket_fill(const u32* __restrict__ pairs, const int* __restrict__ gcursor,
                              int cap, int bits, int N, const int* __restrict__ rowptr,
                              int* __restrict__ csr) {
    __shared__ int cur[2048];
    int b = blockIdx.x, t = threadIdx.x;
    int range = 1 << bits;
    int base = b << bits;
    for (int i = t; i < range; i += 256) {
        int v = base + i;
        cur[i] = (v < N) ? rowptr[v] : 0;
    }
    __syncthreads();
    int n = gcursor[b];
    const u32* p = pairs + (size_t)b * cap;
    for (int i = t; i < n; i += 256) {
        u32 u = p[i];
        int pos = atomicAdd(&cur[u >> 21], 1);
        csr[pos] = (int)(u & 0x1FFFFFu);
    }
}

// ---------------- per-node matmul, pre-scaled by dis[v] ----------------
template <int FIN, int FOUT, bool EXT>
__global__ void k_matmul(const void* __restrict__ xin, const int* __restrict__ gidx,
                         const bf16* __restrict__ actin,
                         const void* __restrict__ W, const float* __restrict__ dis,
                         bf16* __restrict__ g, const int* __restrict__ flag, int n) {
    __shared__ float Ws[FIN * FOUT];
    const int f32m = flag[0];
    for (int i = threadIdx.x; i < FIN * FOUT; i += blockDim.x)
        Ws[i] = f32m ? ((const float*)W)[i] : b2f(((const bf16*)W)[i]);
    __syncthreads();
    int v = blockIdx.x * blockDim.x + threadIdx.x;
    if (v >= n) return;

    float x[FIN];
    if (EXT) {
        if (f32m) {
            const float* p = (const float*)xin;
            #pragma unroll
            for (int k = 0; k < FIN; k++) x[k] = p[(size_t)v * FIN + k];
        } else {
            const bf16* p = (const bf16*)xin;
            #pragma unroll
            for (int k = 0; k < FIN; k++) x[k] = b2f(p[(size_t)v * FIN + k]);
        }
    } else {
        int row = gidx[v];
        #pragma unroll
        for (int k = 0; k < FIN; k++) x[k] = b2f(actin[(size_t)row * FIN + k]);
    }

    float y[FOUT];
    #pragma unroll
    for (int f = 0; f < FOUT; f++) y[f] = 0.f;
    #pragma unroll
    for (int k = 0; k < FIN; k++) {
        float xk = x[k];
        #pragma unroll
        for (int f = 0; f < FOUT; f++) y[f] = fmaf(xk, Ws[k * FOUT + f], y[f]);
    }

    float dv = dis[v];
    #pragma unroll
    for (int f = 0; f < FOUT; f++)
        g[(size_t)v * FOUT + f] = __float2bfloat16(dv * y[f]);
}

// ---------------- CSR gather + finalize, 4-way batched loads ----------------
// act[v,f] = relu( dis[v] * (g[v,f] + sum_{u in N(v)} g[u,f]) + b[f] )
// 4 csr loads then 4 independent g-row loads in flight per thread.
template <int FOUT>
__global__ void k_gather(const bf16* __restrict__ g, const int* __restrict__ rowptr,
                         const int* __restrict__ cnt, const int* __restrict__ csr,
                         const float* __restrict__ dis, const void* __restrict__ bias,
                         bf16* __restrict__ act, const int* __restrict__ flag, int total) {
    int i = blockIdx.x * blockDim.x + threadIdx.x;
    if (i >= total) return;
    int v = i / FOUT;
    int f = i - v * FOUT;
    float s = b2f(g[i]);  // self-loop term
    int r0 = rowptr[v], c = cnt[v];
    int j = 0;
    for (; j + 4 <= c; j += 4) {
        int u0 = csr[r0 + j + 0];
        int u1 = csr[r0 + j + 1];
        int u2 = csr[r0 + j + 2];
        int u3 = csr[r0 + j + 3];
        float a0 = b2f(g[(size_t)u0 * FOUT + f]);
        float a1 = b2f(g[(size_t)u1 * FOUT + f]);
        float a2 = b2f(g[(size_t)u2 * FOUT + f]);
        float a3 = b2f(g[(size_t)u3 * FOUT + f]);
        s += (a0 + a1) + (a2 + a3);
    }
    if (j + 2 <= c) {
        int u0 = csr[r0 + j + 0];
        int u1 = csr[r0 + j + 1];
        float a0 = b2f(g[(size_t)u0 * FOUT + f]);
        float a1 = b2f(g[(size_t)u1 * FOUT + f]);
        s += a0 + a1;
        j += 2;
    }
    if (j < c)
        s += b2f(g[(size_t)csr[r0 + j] * FOUT + f]);
    float bf = flag[0] ? ((const float*)bias)[f] : b2f(((const bf16*)bias)[f]);
    float val = fmaf(dis[v], s, bf);
    act[i] = __float2bfloat16(val > 0.f ? val : 0.f);
}

// ---------------- final unpool gather -> out (dtype per flag) ----------------
__global__ void k_gather_out(const bf16* __restrict__ act, const int* __restrict__ idx,
                             void* __restrict__ out, const int* __restrict__ flag, int n) {
    int u = blockIdx.x * blockDim.x + threadIdx.x;
    if (u >= n) return;
    size_t r = (size_t)idx[u];
    float v0 = b2f(act[3 * r + 0]);
    float v1 = b2f(act[3 * r + 1]);
    float v2 = b2f(act[3 * r + 2]);
    if (flag[0]) {
        float* o = (float*)out;
        o[3 * (size_t)u + 0] = v0; o[3 * (size_t)u + 1] = v1; o[3 * (size_t)u + 2] = v2;
    } else {
        bf16* o = (bf16*)out;
        o[3 * (size_t)u + 0] = __float2bfloat16(v0);
        o[3 * (size_t)u + 1] = __float2bfloat16(v1);
        o[3 * (size_t)u + 2] = __float2bfloat16(v2);
    }
}

// ---------------- host-side stage driver ----------------
struct Ws {
    int* flag; float* dis; int* cnt; int* rowptr; int* partial; int* gcursor;
    int* csr; u32* pairs; bf16* g; /* g aliases pairs */ bf16* act;
};

static inline int cdiv(long long a, long long b) { return (int)((a + b - 1) / b); }

static inline int range_bits_for(int N) {
    int bits = 8;
    while (cdiv(N, 1 << bits) > 512) bits++;
    return bits;
}

template <int FIN, int FOUT, bool EXT>
static void run_stage(const void* xin, const int* gidx, const bf16* actin,
                      const void* W, const void* bias,
                      const int* src, const int* dst, int E, int N,
                      const Ws& w, hipStream_t stream) {
    const int B = 256;
    int bits = range_bits_for(N);
    int nb = cdiv(N, 1 << bits);
    int cap = E / nb + E / (4 * nb) + 256;
    int nScanBlocks = cdiv(N, 1024);

    k_zero<<<1, 512, 0, stream>>>(w.gcursor, 512);
    k_partition<<<cdiv(E, TILE), B, 0, stream>>>(src, dst, E, bits, cap, w.gcursor, w.pairs);
    k_bucket_count<<<nb, B, 0, stream>>>(w.pairs, w.gcursor, cap, bits, N, w.cnt);
    k_scan_partial<<<nScanBlocks, B, 0, stream>>>(w.cnt, w.partial, N);
    k_scan_block<<<1, 1024, 0, stream>>>(w.partial, nScanBlocks);
    k_scan_final<<<nScanBlocks, B, 0, stream>>>(w.cnt, w.partial, w.rowptr, w.dis, N);
    k_bucket_fill<<<nb, B, 0, stream>>>(w.pairs, w.gcursor, cap, bits, N, w.rowptr, w.csr);
    // g aliases pairs: pairs dead after k_bucket_fill
    k_matmul<FIN, FOUT, EXT><<<cdiv(N, B), B, 0, stream>>>(xin, gidx, actin, W, w.dis, w.g, w.flag, N);
    k_gather<FOUT><<<cdiv((long long)N * FOUT, B), B, 0, stream>>>(
        w.g, w.rowptr, w.cnt, w.csr, w.dis, bias, w.act, w.flag, N * FOUT);
}

extern "C" void kernel_launch(void* const* d_in, const int* in_sizes, int n_in,
                              void* d_out, int out_size, void* d_ws, size_t ws_size,
                              hipStream_t stream) {
    const void* x  = d_in[0];
    const void* W1 = d_in[1]; const void* b1 = d_in[2];
    const void* W2 = d_in[3]; const void* b2 = d_in[4];
    const void* W3 = d_in[5]; const void* b3 = d_in[6];
    const void* W4 = d_in[7]; const void* b4 = d_in[8];
    const int* e0  = (const int*)d_in[9];
    const int* up1 = (const int*)d_in[10];
    const int* e1  = (const int*)d_in[11];
    const int* up2 = (const int*)d_in[12];
    const int* e2  = (const int*)d_in[13];
    const int* up3 = (const int*)d_in[14];
    const int* e3  = (const int*)d_in[15];
    const int* up4 = (const int*)d_in[16];

    const int N0 = in_sizes[0] / 3;
    const int N1 = in_sizes[10];
    const int N2 = in_sizes[12];
    const int N3 = in_sizes[14];
    const int N4 = in_sizes[16];
    const int E0 = in_sizes[9] / 2, E1 = in_sizes[11] / 2;
    const int E2 = in_sizes[13] / 2, E3 = in_sizes[15] / 2;

    // capacities
    size_t CAP = (size_t)N0 * 32;
    if ((size_t)N1 * 64 > CAP) CAP = (size_t)N1 * 64;
    if ((size_t)N2 * 32 > CAP) CAP = (size_t)N2 * 32;
    if ((size_t)N3 * 3  > CAP) CAP = (size_t)N3 * 3;
    size_t maxN = (size_t)(N3 > N2 ? N3 : N2);
    if ((size_t)N1 > maxN) maxN = N1;
    if ((size_t)N0 > maxN) maxN = N0;
    size_t maxE = (size_t)(E3 > E2 ? E3 : E2);
    if ((size_t)E1 > maxE) maxE = E1;
    if ((size_t)E0 > maxE) maxE = E0;
    size_t maxN4 = (maxN + 3) & ~(size_t)3;

    // max pairs capacity over stages
    size_t maxPairs = 0;
    {
        int Ns[4] = {N0, N1, N2, N3};
        int Es[4] = {E0, E1, E2, E3};
        for (int s = 0; s < 4; s++) {
            int bits = range_bits_for(Ns[s]);
            int nb = cdiv(Ns[s], 1 << bits);
            size_t cap = (size_t)(Es[s] / nb + Es[s] / (4 * nb) + 256);
            size_t tot = cap * (size_t)nb;
            if (tot > maxPairs) maxPairs = tot;
        }
    }

    // workspace layout (~80 MB): pairs/g share a union region
    size_t uBytes = maxPairs * 4;
    if (CAP * 2 > uBytes) uBytes = CAP * 2;
    uBytes = (uBytes + 255) & ~(size_t)255;

    char* p = (char*)d_ws;
    Ws w;
    w.flag    = (int*)p;            p += 256;
    w.dis     = (float*)p;          p += maxN4 * 4;
    w.cnt     = (int*)p;            p += maxN4 * 4;
    w.rowptr  = (int*)p;            p += maxN4 * 4;
    w.partial = (int*)p;            p += 4096 * 4;
    w.gcursor = (int*)p;            p += 1024 * 4;
    w.csr     = (int*)p;            p += ((maxE + 3) & ~(size_t)3) * 4;
    w.pairs   = (u32*)p;
    w.g       = (bf16*)p;           p += uBytes;
    w.act     = (bf16*)p;           // CAP bf16

    const int B = 256;

    k_detect<<<1, 256, 0, stream>>>((const u16*)x, w.flag);

    // stage 1: x @ W1 -> 32, graph e0 (N0)
    run_stage<3, 32, true>(x, nullptr, nullptr, W1, b1, e0, e0 + E0, E0, N0, w, stream);
    // stage 2: act1[up1] @ W2 -> 64, graph e1 (N1)
    run_stage<32, 64, false>(nullptr, up1, w.act, W2, b2, e1, e1 + E1, E1, N1, w, stream);
    // stage 3: act2[up2] @ W3 -> 32, graph e2 (N2)
    run_stage<64, 32, false>(nullptr, up2, w.act, W3, b3, e2, e2 + E2, E2, N2, w, stream);
    // stage 4: act3[up3] @ W4 -> 3, graph e3 (N3)
    run_stage<32, 3, false>(nullptr, up3, w.act, W4, b4, e3, e3 + E3, E3, N3, w, stream);

    // final unpool
    k_gather_out<<<cdiv(N4, B), B, 0, stream>>>(w.act, up4, d_out, w.flag, N4);
}

// Round 7
// 794.828 us; speedup vs baseline: 2.1624x; 1.0783x over previous
//
#include <hip/hip_runtime.h>
#include <hip/hip_bf16.h>

typedef __hip_bfloat16 bf16;
typedef unsigned short u16;
typedef unsigned int u32;

static __device__ __forceinline__ float b2f(bf16 v) { return __bfloat162float(v); }

#define TILE 4096   // edges per partition block (32 KB LDS staging)

// ---------------- dtype detection ----------------
__global__ void k_detect(const u16* __restrict__ xraw, int* __restrict__ flag) {
    __shared__ int s;
    if (threadIdx.x == 0) s = 0;
    __syncthreads();
    u16 u = xraw[threadIdx.x];
    int e = (u >> 7) & 0xFF;
    if (e >= 0x8F) atomicAdd(&s, 1);
    __syncthreads();
    if (threadIdx.x == 0) flag[0] = (s > 0) ? 1 : 0;
}

__global__ void k_zero(int* __restrict__ a, int n) {
    int i = blockIdx.x * blockDim.x + threadIdx.x;
    if (i < n) a[i] = 0;
}

// ---------------- pass A: partition edges into dst-range buckets ----------------
// LDS-staged reorder: group the tile's pairs by bucket in LDS first, then
// write each bucket run contiguously -> line-coalesced global writes (amp ~1).
// pairs[bucket*cap + slot] = (bucket_local_dst << 21) | src
__global__ void k_partition(const int* __restrict__ src, const int* __restrict__ dst,
                            int E, int bits, int cap,
                            int* __restrict__ gcursor, u32* __restrict__ pairs) {
    __shared__ u32 stage[TILE];   // 16 KB
    __shared__ u16 bkt[TILE];     //  8 KB
    __shared__ int hist[512];
    __shared__ int lofs[512];
    __shared__ int gbase[512];
    __shared__ int lcur[512];
    __shared__ int tmp[256];

    int t = threadIdx.x;
    int e0 = blockIdx.x * TILE;
    int e1 = min(e0 + TILE, E);
    int n = e1 - e0;

    for (int i = t; i < 512; i += 256) hist[i] = 0;
    __syncthreads();
    for (int i = t; i < n; i += 256)
        atomicAdd(&hist[dst[e0 + i] >> bits], 1);
    __syncthreads();

    // block-local exclusive scan of hist (512 bins, 256 threads, 2 bins/thread)
    int a0 = hist[2 * t], a1 = hist[2 * t + 1];
    int s = a0 + a1;
    tmp[t] = s; __syncthreads();
    for (int off = 1; off < 256; off <<= 1) {
        int v = (t >= off) ? tmp[t - off] : 0;
        __syncthreads();
        tmp[t] += v;
        __syncthreads();
    }
    int base = tmp[t] - s;  // exclusive over pairs of bins
    lofs[2 * t] = base;
    lofs[2 * t + 1] = base + a0;
    __syncthreads();

    // reserve global runs + init local cursors
    for (int i = t; i < 512; i += 256) {
        int h = hist[i];
        gbase[i] = h ? atomicAdd(&gcursor[i], h) : 0;
        lcur[i] = lofs[i];
    }
    __syncthreads();

    // scatter into LDS stage, grouped by bucket
    u32 mask = (1u << bits) - 1u;
    for (int i = t; i < n; i += 256) {
        int d = dst[e0 + i];
        int b = d >> bits;
        int pos = atomicAdd(&lcur[b], 1);
        stage[pos] = (((u32)d & mask) << 21) | (u32)src[e0 + i];
        bkt[pos] = (u16)b;
    }
    __syncthreads();

    // coalesced write-out: consecutive i in a bucket -> consecutive global pos
    for (int i = t; i < n; i += 256) {
        int b = bkt[i];
        pairs[(size_t)b * cap + gbase[b] + (i - lofs[b])] = stage[i];
    }
}

// ---------------- pass B1: per-bucket histogram -> cnt ----------------
__global__ void k_bucket_count(const u32* __restrict__ pairs, const int* __restrict__ gcursor,
                               int cap, int bits, int N, int* __restrict__ cnt) {
    __shared__ int hist[2048];
    int b = blockIdx.x, t = threadIdx.x;
    int range = 1 << bits;
    for (int i = t; i < range; i += 256) hist[i] = 0;
    __syncthreads();
    int n = gcursor[b];
    const u32* p = pairs + (size_t)b * cap;
    for (int i = t; i < n; i += 256)
        atomicAdd(&hist[p[i] >> 21], 1);
    __syncthreads();
    int base = b << bits;
    for (int i = t; i < range; i += 256) {
        int v = base + i;
        if (v < N) cnt[v] = hist[i];
    }
}

// ---------------- global exclusive scan of cnt -> rowptr (+dis) ----------------
__global__ void k_scan_partial(const int* __restrict__ cnt, int* __restrict__ partial, int n) {
    __shared__ int lds[256];
    int t = threadIdx.x;
    int base = blockIdx.x * 1024 + t * 4;
    int s = 0;
    #pragma unroll
    for (int k = 0; k < 4; k++) { int i = base + k; if (i < n) s += cnt[i]; }
    lds[t] = s; __syncthreads();
    for (int off = 128; off > 0; off >>= 1) {
        if (t < off) lds[t] += lds[t + off];
        __syncthreads();
    }
    if (t == 0) partial[blockIdx.x] = lds[0];
}

__global__ void k_scan_block(int* __restrict__ partial, int m) {
    __shared__ int lds[1024];
    int t = threadIdx.x;
    int v = (t < m) ? partial[t] : 0;
    lds[t] = v; __syncthreads();
    for (int off = 1; off < 1024; off <<= 1) {
        int tmp = (t >= off) ? lds[t - off] : 0;
        __syncthreads();
        lds[t] += tmp;
        __syncthreads();
    }
    if (t < m) partial[t] = lds[t] - v;  // exclusive
}

__global__ void k_scan_final(const int* __restrict__ cnt, const int* __restrict__ partial,
                             int* __restrict__ rowptr, float* __restrict__ dis, int n) {
    __shared__ int lds[256];
    int t = threadIdx.x;
    int base = blockIdx.x * 1024 + t * 4;
    int a[4]; int s = 0;
    #pragma unroll
    for (int k = 0; k < 4; k++) { int i = base + k; a[k] = (i < n) ? cnt[i] : 0; s += a[k]; }
    lds[t] = s; __syncthreads();
    for (int off = 1; off < 256; off <<= 1) {
        int tmp = (t >= off) ? lds[t - off] : 0;
        __syncthreads();
        lds[t] += tmp;
        __syncthreads();
    }
    int run = partial[blockIdx.x] + lds[t] - s;
    #pragma unroll
    for (int k = 0; k < 4; k++) {
        int i = base + k;
        if (i < n) {
            rowptr[i] = run;
            dis[i] = rsqrtf((float)(a[k] + 1));
            run += a[k];
        }
    }
}

// ---------------- pass B2: per-bucket scatter into contiguous csr span ----------------
__global__ void k_bucket_fill(const u32* __restrict__ pairs, const int* __restrict__ gcursor,
                              int cap, int bits, int N, const int* __restrict__ rowptr,
                              int* __restrict__ csr) {
    __shared__ int cur[2048];
    int b = blockIdx.x, t = threadIdx.x;
    int range = 1 << bits;
    int base = b << bits;
    for (int i = t; i < range; i += 256) {
        int v = base + i;
        cur[i] = (v < N) ? rowptr[v] : 0;
    }
    __syncthreads();
    int n = gcursor[b];
    const u32* p = pairs + (size_t)b * cap;
    for (int i = t; i < n; i += 256) {
        u32 u = p[i];
        int pos = atomicAdd(&cur[u >> 21], 1);
        csr[pos] = (int)(u & 0x1FFFFFu);
    }
}

// ---------------- per-node matmul, pre-scaled by dis[v] ----------------
template <int FIN, int FOUT, bool EXT>
__global__ void k_matmul(const void* __restrict__ xin, const int* __restrict__ gidx,
                         const bf16* __restrict__ actin,
                         const void* __restrict__ W, const float* __restrict__ dis,
                         bf16* __restrict__ g, const int* __restrict__ flag, int n) {
    __shared__ float Ws[FIN * FOUT];
    const int f32m = flag[0];
    for (int i = threadIdx.x; i < FIN * FOUT; i += blockDim.x)
        Ws[i] = f32m ? ((const float*)W)[i] : b2f(((const bf16*)W)[i]);
    __syncthreads();
    int v = blockIdx.x * blockDim.x + threadIdx.x;
    if (v >= n) return;

    float x[FIN];
    if (EXT) {
        if (f32m) {
            const float* p = (const float*)xin;
            #pragma unroll
            for (int k = 0; k < FIN; k++) x[k] = p[(size_t)v * FIN + k];
        } else {
            const bf16* p = (const bf16*)xin;
            #pragma unroll
            for (int k = 0; k < FIN; k++) x[k] = b2f(p[(size_t)v * FIN + k]);
        }
    } else {
        int row = gidx[v];
        #pragma unroll
        for (int k = 0; k < FIN; k++) x[k] = b2f(actin[(size_t)row * FIN + k]);
    }

    float y[FOUT];
    #pragma unroll
    for (int f = 0; f < FOUT; f++) y[f] = 0.f;
    #pragma unroll
    for (int k = 0; k < FIN; k++) {
        float xk = x[k];
        #pragma unroll
        for (int f = 0; f < FOUT; f++) y[f] = fmaf(xk, Ws[k * FOUT + f], y[f]);
    }

    float dv = dis[v];
    #pragma unroll
    for (int f = 0; f < FOUT; f++)
        g[(size_t)v * FOUT + f] = __float2bfloat16(dv * y[f]);
}

// ---------------- CSR gather + finalize, 4-way batched loads ----------------
template <int FOUT>
__global__ void k_gather(const bf16* __restrict__ g, const int* __restrict__ rowptr,
                         const int* __restrict__ cnt, const int* __restrict__ csr,
                         const float* __restrict__ dis, const void* __restrict__ bias,
                         bf16* __restrict__ act, const int* __restrict__ flag, int total) {
    int i = blockIdx.x * blockDim.x + threadIdx.x;
    if (i >= total) return;
    int v = i / FOUT;
    int f = i - v * FOUT;
    float s = b2f(g[i]);  // self-loop term
    int r0 = rowptr[v], c = cnt[v];
    int j = 0;
    for (; j + 4 <= c; j += 4) {
        int u0 = csr[r0 + j + 0];
        int u1 = csr[r0 + j + 1];
        int u2 = csr[r0 + j + 2];
        int u3 = csr[r0 + j + 3];
        float a0 = b2f(g[(size_t)u0 * FOUT + f]);
        float a1 = b2f(g[(size_t)u1 * FOUT + f]);
        float a2 = b2f(g[(size_t)u2 * FOUT + f]);
        float a3 = b2f(g[(size_t)u3 * FOUT + f]);
        s += (a0 + a1) + (a2 + a3);
    }
    if (j + 2 <= c) {
        int u0 = csr[r0 + j + 0];
        int u1 = csr[r0 + j + 1];
        float a0 = b2f(g[(size_t)u0 * FOUT + f]);
        float a1 = b2f(g[(size_t)u1 * FOUT + f]);
        s += a0 + a1;
        j += 2;
    }
    if (j < c)
        s += b2f(g[(size_t)csr[r0 + j] * FOUT + f]);
    float bf = flag[0] ? ((const float*)bias)[f] : b2f(((const bf16*)bias)[f]);
    float val = fmaf(dis[v], s, bf);
    act[i] = __float2bfloat16(val > 0.f ? val : 0.f);
}

// ---------------- final unpool gather -> out (dtype per flag) ----------------
__global__ void k_gather_out(const bf16* __restrict__ act, const int* __restrict__ idx,
                             void* __restrict__ out, const int* __restrict__ flag, int n) {
    int u = blockIdx.x * blockDim.x + threadIdx.x;
    if (u >= n) return;
    size_t r = (size_t)idx[u];
    float v0 = b2f(act[3 * r + 0]);
    float v1 = b2f(act[3 * r + 1]);
    float v2 = b2f(act[3 * r + 2]);
    if (flag[0]) {
        float* o = (float*)out;
        o[3 * (size_t)u + 0] = v0; o[3 * (size_t)u + 1] = v1; o[3 * (size_t)u + 2] = v2;
    } else {
        bf16* o = (bf16*)out;
        o[3 * (size_t)u + 0] = __float2bfloat16(v0);
        o[3 * (size_t)u + 1] = __float2bfloat16(v1);
        o[3 * (size_t)u + 2] = __float2bfloat16(v2);
    }
}

// ---------------- host-side stage driver ----------------
struct Ws {
    int* flag; float* dis; int* cnt; int* rowptr; int* partial; int* gcursor;
    int* csr; u32* pairs; bf16* g; /* g aliases pairs */ bf16* act;
};

static inline int cdiv(long long a, long long b) { return (int)((a + b - 1) / b); }

static inline int range_bits_for(int N) {
    int bits = 8;
    while (cdiv(N, 1 << bits) > 512) bits++;
    return bits;
}

template <int FIN, int FOUT, bool EXT>
static void run_stage(const void* xin, const int* gidx, const bf16* actin,
                      const void* W, const void* bias,
                      const int* src, const int* dst, int E, int N,
                      const Ws& w, hipStream_t stream) {
    const int B = 256;
    int bits = range_bits_for(N);
    int nb = cdiv(N, 1 << bits);
    int cap = E / nb + E / (4 * nb) + 256;
    int nScanBlocks = cdiv(N, 1024);

    k_zero<<<1, 512, 0, stream>>>(w.gcursor, 512);
    k_partition<<<cdiv(E, TILE), B, 0, stream>>>(src, dst, E, bits, cap, w.gcursor, w.pairs);
    k_bucket_count<<<nb, B, 0, stream>>>(w.pairs, w.gcursor, cap, bits, N, w.cnt);
    k_scan_partial<<<nScanBlocks, B, 0, stream>>>(w.cnt, w.partial, N);
    k_scan_block<<<1, 1024, 0, stream>>>(w.partial, nScanBlocks);
    k_scan_final<<<nScanBlocks, B, 0, stream>>>(w.cnt, w.partial, w.rowptr, w.dis, N);
    k_bucket_fill<<<nb, B, 0, stream>>>(w.pairs, w.gcursor, cap, bits, N, w.rowptr, w.csr);
    // g aliases pairs: pairs dead after k_bucket_fill
    k_matmul<FIN, FOUT, EXT><<<cdiv(N, B), B, 0, stream>>>(xin, gidx, actin, W, w.dis, w.g, w.flag, N);
    k_gather<FOUT><<<cdiv((long long)N * FOUT, B), B, 0, stream>>>(
        w.g, w.rowptr, w.cnt, w.csr, w.dis, bias, w.act, w.flag, N * FOUT);
}

extern "C" void kernel_launch(void* const* d_in, const int* in_sizes, int n_in,
                              void* d_out, int out_size, void* d_ws, size_t ws_size,
                              hipStream_t stream) {
    const void* x  = d_in[0];
    const void* W1 = d_in[1]; const void* b1 = d_in[2];
    const void* W2 = d_in[3]; const void* b2 = d_in[4];
    const void* W3 = d_in[5]; const void* b3 = d_in[6];
    const void* W4 = d_in[7]; const void* b4 = d_in[8];
    const int* e0  = (const int*)d_in[9];
    const int* up1 = (const int*)d_in[10];
    const int* e1  = (const int*)d_in[11];
    const int* up2 = (const int*)d_in[12];
    const int* e2  = (const int*)d_in[13];
    const int* up3 = (const int*)d_in[14];
    const int* e3  = (const int*)d_in[15];
    const int* up4 = (const int*)d_in[16];

    const int N0 = in_sizes[0] / 3;
    const int N1 = in_sizes[10];
    const int N2 = in_sizes[12];
    const int N3 = in_sizes[14];
    const int N4 = in_sizes[16];
    const int E0 = in_sizes[9] / 2, E1 = in_sizes[11] / 2;
    const int E2 = in_sizes[13] / 2, E3 = in_sizes[15] / 2;

    // capacities
    size_t CAP = (size_t)N0 * 32;
    if ((size_t)N1 * 64 > CAP) CAP = (size_t)N1 * 64;
    if ((size_t)N2 * 32 > CAP) CAP = (size_t)N2 * 32;
    if ((size_t)N3 * 3  > CAP) CAP = (size_t)N3 * 3;
    size_t maxN = (size_t)(N3 > N2 ? N3 : N2);
    if ((size_t)N1 > maxN) maxN = N1;
    if ((size_t)N0 > maxN) maxN = N0;
    size_t maxE = (size_t)(E3 > E2 ? E3 : E2);
    if ((size_t)E1 > maxE) maxE = E1;
    if ((size_t)E0 > maxE) maxE = E0;
    size_t maxN4 = (maxN + 3) & ~(size_t)3;

    // max pairs capacity over stages
    size_t maxPairs = 0;
    {
        int Ns[4] = {N0, N1, N2, N3};
        int Es[4] = {E0, E1, E2, E3};
        for (int s = 0; s < 4; s++) {
            int bits = range_bits_for(Ns[s]);
            int nb = cdiv(Ns[s], 1 << bits);
            size_t cap = (size_t)(Es[s] / nb + Es[s] / (4 * nb) + 256);
            size_t tot = cap * (size_t)nb;
            if (tot > maxPairs) maxPairs = tot;
        }
    }

    // workspace layout (~80 MB): pairs/g share a union region
    size_t uBytes = maxPairs * 4;
    if (CAP * 2 > uBytes) uBytes = CAP * 2;
    uBytes = (uBytes + 255) & ~(size_t)255;

    char* p = (char*)d_ws;
    Ws w;
    w.flag    = (int*)p;            p += 256;
    w.dis     = (float*)p;          p += maxN4 * 4;
    w.cnt     = (int*)p;            p += maxN4 * 4;
    w.rowptr  = (int*)p;            p += maxN4 * 4;
    w.partial = (int*)p;            p += 4096 * 4;
    w.gcursor = (int*)p;            p += 1024 * 4;
    w.csr     = (int*)p;            p += ((maxE + 3) & ~(size_t)3) * 4;
    w.pairs   = (u32*)p;
    w.g       = (bf16*)p;           p += uBytes;
    w.act     = (bf16*)p;           // CAP bf16

    const int B = 256;

    k_detect<<<1, 256, 0, stream>>>((const u16*)x, w.flag);

    // stage 1: x @ W1 -> 32, graph e0 (N0)
    run_stage<3, 32, true>(x, nullptr, nullptr, W1, b1, e0, e0 + E0, E0, N0, w, stream);
    // stage 2: act1[up1] @ W2 -> 64, graph e1 (N1)
    run_stage<32, 64, false>(nullptr, up1, w.act, W2, b2, e1, e1 + E1, E1, N1, w, stream);
    // stage 3: act2[up2] @ W3 -> 32, graph e2 (N2)
    run_stage<64, 32, false>(nullptr, up2, w.act, W3, b3, e2, e2 + E2, E2, N2, w, stream);
    // stage 4: act3[up3] @ W4 -> 3, graph e3 (N3)
    run_stage<32, 3, false>(nullptr, up3, w.act, W4, b4, e3, e3 + E3, E3, N3, w, stream);

    // final unpool
    k_gather_out<<<cdiv(N4, B), B, 0, stream>>>(w.act, up4, d_out, w.flag, N4);
}

// Round 8
// 715.705 us; speedup vs baseline: 2.4014x; 1.1106x over previous
//
#include <hip/hip_runtime.h>
#include <hip/hip_bf16.h>

typedef __hip_bfloat16 bf16;
typedef unsigned short u16;
typedef unsigned int u32;

static __device__ __forceinline__ float b2f(bf16 v) { return __bfloat162float(v); }

#define TILE 4096   // edges per partition block (LDS staging)

// ---------------- dtype detection ----------------
__global__ void k_detect(const u16* __restrict__ xraw, int* __restrict__ flag) {
    __shared__ int s;
    if (threadIdx.x == 0) s = 0;
    __syncthreads();
    u16 u = xraw[threadIdx.x];
    int e = (u >> 7) & 0xFF;
    if (e >= 0x8F) atomicAdd(&s, 1);
    __syncthreads();
    if (threadIdx.x == 0) flag[0] = (s > 0) ? 1 : 0;
}

__global__ void k_zero(int* __restrict__ a, int n) {
    int i = blockIdx.x * blockDim.x + threadIdx.x;
    if (i < n) a[i] = 0;
}

// ---------------- pass A: partition edges into dst-range buckets ----------------
// LDS-staged reorder -> line-coalesced global writes.
// pairs[bucket*cap + slot] = (bucket_local_dst << 21) | src
__global__ void k_partition(const int* __restrict__ src, const int* __restrict__ dst,
                            int E, int bits, int cap,
                            int* __restrict__ gcursor, u32* __restrict__ pairs) {
    __shared__ u32 stage[TILE];
    __shared__ u16 bkt[TILE];
    __shared__ int hist[512];
    __shared__ int lofs[512];
    __shared__ int gbase[512];
    __shared__ int lcur[512];
    __shared__ int tmp[256];

    int t = threadIdx.x;
    int e0 = blockIdx.x * TILE;
    int e1 = min(e0 + TILE, E);
    int n = e1 - e0;

    for (int i = t; i < 512; i += 256) hist[i] = 0;
    __syncthreads();
    for (int i = t; i < n; i += 256)
        atomicAdd(&hist[dst[e0 + i] >> bits], 1);
    __syncthreads();

    int a0 = hist[2 * t], a1 = hist[2 * t + 1];
    int s = a0 + a1;
    tmp[t] = s; __syncthreads();
    for (int off = 1; off < 256; off <<= 1) {
        int v = (t >= off) ? tmp[t - off] : 0;
        __syncthreads();
        tmp[t] += v;
        __syncthreads();
    }
    int base = tmp[t] - s;
    lofs[2 * t] = base;
    lofs[2 * t + 1] = base + a0;
    __syncthreads();

    for (int i = t; i < 512; i += 256) {
        int h = hist[i];
        gbase[i] = h ? atomicAdd(&gcursor[i], h) : 0;
        lcur[i] = lofs[i];
    }
    __syncthreads();

    u32 mask = (1u << bits) - 1u;
    for (int i = t; i < n; i += 256) {
        int d = dst[e0 + i];
        int b = d >> bits;
        int pos = atomicAdd(&lcur[b], 1);
        stage[pos] = (((u32)d & mask) << 21) | (u32)src[e0 + i];
        bkt[pos] = (u16)b;
    }
    __syncthreads();

    for (int i = t; i < n; i += 256) {
        int b = bkt[i];
        pairs[(size_t)b * cap + gbase[b] + (i - lofs[b])] = stage[i];
    }
}

// ---------------- fused pass B: count + scan + rowptr/cnt/dis + fill ----------------
// Each block: (1) redundantly scans gcursor[0..511] for its bucket's global
// base, (2) LDS-hists its bucket, (3) LDS-scans bins, (4) writes
// rowptr/cnt/dis coalesced, (5) fills its contiguous csr span.
__global__ void k_bucket_build(const u32* __restrict__ pairs, const int* __restrict__ gcursor,
                               int cap, int bits, int N,
                               int* __restrict__ rowptr, int* __restrict__ cnt,
                               float* __restrict__ dis, int* __restrict__ csr) {
    __shared__ int hist[2048];
    __shared__ int ofs[2048];
    __shared__ int tmp[256];
    __shared__ int bscan[512];

    int b = blockIdx.x, t = threadIdx.x;
    int range = 1 << bits;

    // bucket-base scan over 512 gcursor totals
    {
        int v0 = gcursor[2 * t], v1 = gcursor[2 * t + 1];
        int s = v0 + v1;
        tmp[t] = s; __syncthreads();
        for (int off = 1; off < 256; off <<= 1) {
            int v = (t >= off) ? tmp[t - off] : 0;
            __syncthreads();
            tmp[t] += v;
            __syncthreads();
        }
        int base = tmp[t] - s;
        bscan[2 * t] = base;
        bscan[2 * t + 1] = base + v0;
        __syncthreads();
    }
    int bbase = bscan[b];
    int tot = gcursor[b];

    for (int i = t; i < range; i += 256) hist[i] = 0;
    __syncthreads();
    const u32* p = pairs + (size_t)b * cap;
    for (int i = t; i < tot; i += 256)
        atomicAdd(&hist[p[i] >> 21], 1);
    __syncthreads();

    // exclusive scan of `range` bins (bpt = range/256 bins per thread, <=8)
    int bpt = range >> 8;
    int lbase = t * bpt;
    int s = 0;
    #pragma unroll 8
    for (int k = 0; k < 8; k++) if (k < bpt) s += hist[lbase + k];
    tmp[t] = s; __syncthreads();
    for (int off = 1; off < 256; off <<= 1) {
        int v = (t >= off) ? tmp[t - off] : 0;
        __syncthreads();
        tmp[t] += v;
        __syncthreads();
    }
    int run = tmp[t] - s;
    #pragma unroll 8
    for (int k = 0; k < 8; k++) if (k < bpt) {
        ofs[lbase + k] = run;
        run += hist[lbase + k];
    }
    __syncthreads();

    int nbase = b << bits;
    for (int i = t; i < range; i += 256) {
        int v = nbase + i;
        if (v < N) {
            int h = hist[i];
            rowptr[v] = bbase + ofs[i];
            cnt[v] = h;
            dis[v] = rsqrtf((float)(h + 1));
        }
    }
    // reuse hist as local cursor
    for (int i = t; i < range; i += 256) hist[i] = ofs[i];
    __syncthreads();
    for (int i = t; i < tot; i += 256) {
        u32 u = p[i];
        int pos = atomicAdd(&hist[u >> 21], 1);
        csr[bbase + pos] = (int)(u & 0x1FFFFFu);
    }
}

// ---------------- pre-scale: g[v,f] = dis[v] * x_in[row(v), f] ----------------
template <int F, bool EXT>
__global__ void k_pre(const void* __restrict__ xin, const int* __restrict__ gidx,
                      const bf16* __restrict__ actin, const float* __restrict__ dis,
                      bf16* __restrict__ g, const int* __restrict__ flag, int total) {
    int i = blockIdx.x * blockDim.x + threadIdx.x;
    if (i >= total) return;
    int v = i / F;
    int f = i - v * F;
    float x;
    if (EXT) {
        if (flag[0]) x = ((const float*)xin)[i];
        else         x = b2f(((const bf16*)xin)[i]);
    } else {
        int row = gidx[v];
        x = b2f(actin[(size_t)row * F + f]);
    }
    g[i] = __float2bfloat16(dis[v] * x);
}

// ---------------- W-first matmul: g[v,:] = bf16(dis[v] * (act[gidx(v)] @ W)) ----------------
template <int FIN, int FOUT>
__global__ void k_matmul(const int* __restrict__ gidx, const bf16* __restrict__ actin,
                         const void* __restrict__ W, const float* __restrict__ dis,
                         bf16* __restrict__ g, const int* __restrict__ flag, int n) {
    __shared__ float Ws[FIN * FOUT];
    const int f32m = flag[0];
    for (int i = threadIdx.x; i < FIN * FOUT; i += blockDim.x)
        Ws[i] = f32m ? ((const float*)W)[i] : b2f(((const bf16*)W)[i]);
    __syncthreads();
    int v = blockIdx.x * blockDim.x + threadIdx.x;
    if (v >= n) return;
    int row = gidx[v];
    float x[FIN];
    #pragma unroll
    for (int k = 0; k < FIN; k++) x[k] = b2f(actin[(size_t)row * FIN + k]);
    float y[FOUT];
    #pragma unroll
    for (int f = 0; f < FOUT; f++) y[f] = 0.f;
    #pragma unroll
    for (int k = 0; k < FIN; k++) {
        float xk = x[k];
        #pragma unroll
        for (int f = 0; f < FOUT; f++) y[f] = fmaf(xk, Ws[k * FOUT + f], y[f]);
    }
    float dv = dis[v];
    #pragma unroll
    for (int f = 0; f < FOUT; f++)
        g[(size_t)v * FOUT + f] = __float2bfloat16(dv * y[f]);
}

// ---------------- post matmul (agg-first): act = relu(xt @ W + b) ----------------
template <int FIN, int FOUT>
__global__ void k_matmul_post(const bf16* __restrict__ xt, const void* __restrict__ W,
                              const void* __restrict__ bias, bf16* __restrict__ act,
                              const int* __restrict__ flag, int n) {
    __shared__ float Ws[FIN * FOUT];
    __shared__ float Bs[FOUT];
    const int f32m = flag[0];
    for (int i = threadIdx.x; i < FIN * FOUT; i += blockDim.x)
        Ws[i] = f32m ? ((const float*)W)[i] : b2f(((const bf16*)W)[i]);
    for (int i = threadIdx.x; i < FOUT; i += blockDim.x)
        Bs[i] = f32m ? ((const float*)bias)[i] : b2f(((const bf16*)bias)[i]);
    __syncthreads();
    int v = blockIdx.x * blockDim.x + threadIdx.x;
    if (v >= n) return;
    float x[FIN];
    #pragma unroll
    for (int k = 0; k < FIN; k++) x[k] = b2f(xt[(size_t)v * FIN + k]);
    float y[FOUT];
    #pragma unroll
    for (int f = 0; f < FOUT; f++) y[f] = Bs[f];
    #pragma unroll
    for (int k = 0; k < FIN; k++) {
        float xk = x[k];
        #pragma unroll
        for (int f = 0; f < FOUT; f++) y[f] = fmaf(xk, Ws[k * FOUT + f], y[f]);
    }
    #pragma unroll
    for (int f = 0; f < FOUT; f++)
        act[(size_t)v * FOUT + f] = __float2bfloat16(y[f] > 0.f ? y[f] : 0.f);
}

// ---------------- CSR gather, batched loads; FINALIZE: +bias, relu ----------------
template <int FOUT, bool FINALIZE>
__global__ void k_gather(const bf16* __restrict__ g, const int* __restrict__ rowptr,
                         const int* __restrict__ cnt, const int* __restrict__ csr,
                         const float* __restrict__ dis, const void* __restrict__ bias,
                         bf16* __restrict__ out, const int* __restrict__ flag, int total) {
    int i = blockIdx.x * blockDim.x + threadIdx.x;
    if (i >= total) return;
    int v = i / FOUT;
    int f = i - v * FOUT;
    float s = b2f(g[i]);  // self-loop term
    int r0 = rowptr[v], c = cnt[v];
    int j = 0;
    for (; j + 8 <= c; j += 8) {
        int u0 = csr[r0 + j + 0], u1 = csr[r0 + j + 1];
        int u2 = csr[r0 + j + 2], u3 = csr[r0 + j + 3];
        int u4 = csr[r0 + j + 4], u5 = csr[r0 + j + 5];
        int u6 = csr[r0 + j + 6], u7 = csr[r0 + j + 7];
        float a0 = b2f(g[(size_t)u0 * FOUT + f]);
        float a1 = b2f(g[(size_t)u1 * FOUT + f]);
        float a2 = b2f(g[(size_t)u2 * FOUT + f]);
        float a3 = b2f(g[(size_t)u3 * FOUT + f]);
        float a4 = b2f(g[(size_t)u4 * FOUT + f]);
        float a5 = b2f(g[(size_t)u5 * FOUT + f]);
        float a6 = b2f(g[(size_t)u6 * FOUT + f]);
        float a7 = b2f(g[(size_t)u7 * FOUT + f]);
        s += ((a0 + a1) + (a2 + a3)) + ((a4 + a5) + (a6 + a7));
    }
    if (j + 4 <= c) {
        int u0 = csr[r0 + j + 0], u1 = csr[r0 + j + 1];
        int u2 = csr[r0 + j + 2], u3 = csr[r0 + j + 3];
        float a0 = b2f(g[(size_t)u0 * FOUT + f]);
        float a1 = b2f(g[(size_t)u1 * FOUT + f]);
        float a2 = b2f(g[(size_t)u2 * FOUT + f]);
        float a3 = b2f(g[(size_t)u3 * FOUT + f]);
        s += (a0 + a1) + (a2 + a3);
        j += 4;
    }
    if (j + 2 <= c) {
        int u0 = csr[r0 + j + 0], u1 = csr[r0 + j + 1];
        float a0 = b2f(g[(size_t)u0 * FOUT + f]);
        float a1 = b2f(g[(size_t)u1 * FOUT + f]);
        s += a0 + a1;
        j += 2;
    }
    if (j < c)
        s += b2f(g[(size_t)csr[r0 + j] * FOUT + f]);
    float dv = dis[v];
    if (FINALIZE) {
        float bf = flag[0] ? ((const float*)bias)[f] : b2f(((const bf16*)bias)[f]);
        float val = fmaf(dv, s, bf);
        out[i] = __float2bfloat16(val > 0.f ? val : 0.f);
    } else {
        out[i] = __float2bfloat16(dv * s);
    }
}

// ---------------- final unpool gather -> out (dtype per flag) ----------------
__global__ void k_gather_out(const bf16* __restrict__ act, const int* __restrict__ idx,
                             void* __restrict__ out, const int* __restrict__ flag, int n) {
    int u = blockIdx.x * blockDim.x + threadIdx.x;
    if (u >= n) return;
    size_t r = (size_t)idx[u];
    float v0 = b2f(act[3 * r + 0]);
    float v1 = b2f(act[3 * r + 1]);
    float v2 = b2f(act[3 * r + 2]);
    if (flag[0]) {
        float* o = (float*)out;
        o[3 * (size_t)u + 0] = v0; o[3 * (size_t)u + 1] = v1; o[3 * (size_t)u + 2] = v2;
    } else {
        bf16* o = (bf16*)out;
        o[3 * (size_t)u + 0] = __float2bfloat16(v0);
        o[3 * (size_t)u + 1] = __float2bfloat16(v1);
        o[3 * (size_t)u + 2] = __float2bfloat16(v2);
    }
}

// ---------------- host-side ----------------
struct Ws {
    int* flag; float* dis; int* cnt; int* rowptr; int* gcur;  // gcur: 4 x 512
    int* csr; u32* pairs; bf16* g; /* g aliases pairs */ bf16* act; bf16* xt;
};

static inline int cdiv(long long a, long long b) { return (int)((a + b - 1) / b); }

static inline int range_bits_for(int N) {
    int bits = 8;
    while (cdiv(N, 1 << bits) > 512) bits++;
    return bits;
}

static void build_csr(const int* src, const int* dst, int E, int N, int* gcursor,
                      const Ws& w, hipStream_t stream) {
    int bits = range_bits_for(N);
    int nb = cdiv(N, 1 << bits);
    int cap = E / nb + E / (4 * nb) + 256;
    k_partition<<<cdiv(E, TILE), 256, 0, stream>>>(src, dst, E, bits, cap, gcursor, w.pairs);
    k_bucket_build<<<nb, 256, 0, stream>>>(w.pairs, gcursor, cap, bits, N,
                                           w.rowptr, w.cnt, w.dis, w.csr);
}

extern "C" void kernel_launch(void* const* d_in, const int* in_sizes, int n_in,
                              void* d_out, int out_size, void* d_ws, size_t ws_size,
                              hipStream_t stream) {
    const void* x  = d_in[0];
    const void* W1 = d_in[1]; const void* b1 = d_in[2];
    const void* W2 = d_in[3]; const void* b2 = d_in[4];
    const void* W3 = d_in[5]; const void* b3 = d_in[6];
    const void* W4 = d_in[7]; const void* b4 = d_in[8];
    const int* e0  = (const int*)d_in[9];
    const int* up1 = (const int*)d_in[10];
    const int* e1  = (const int*)d_in[11];
    const int* up2 = (const int*)d_in[12];
    const int* e2  = (const int*)d_in[13];
    const int* up3 = (const int*)d_in[14];
    const int* e3  = (const int*)d_in[15];
    const int* up4 = (const int*)d_in[16];

    const int N0 = in_sizes[0] / 3;
    const int N1 = in_sizes[10];
    const int N2 = in_sizes[12];
    const int N3 = in_sizes[14];
    const int N4 = in_sizes[16];
    const int E0 = in_sizes[9] / 2, E1 = in_sizes[11] / 2;
    const int E2 = in_sizes[13] / 2, E3 = in_sizes[15] / 2;

    // capacities
    size_t CAP = (size_t)N0 * 32;
    if ((size_t)N1 * 64 > CAP) CAP = (size_t)N1 * 64;
    if ((size_t)N2 * 32 > CAP) CAP = (size_t)N2 * 32;
    if ((size_t)N3 * 3  > CAP) CAP = (size_t)N3 * 3;
    size_t XTCAP = (size_t)N0 * 3;
    if ((size_t)N1 * 32 > XTCAP) XTCAP = (size_t)N1 * 32;
    size_t maxN = (size_t)(N3 > N2 ? N3 : N2);
    if ((size_t)N1 > maxN) maxN = N1;
    if ((size_t)N0 > maxN) maxN = N0;
    size_t maxE = (size_t)(E3 > E2 ? E3 : E2);
    if ((size_t)E1 > maxE) maxE = E1;
    if ((size_t)E0 > maxE) maxE = E0;
    size_t maxN4 = (maxN + 3) & ~(size_t)3;

    size_t maxPairs = 0;
    {
        int Ns[4] = {N0, N1, N2, N3};
        int Es[4] = {E0, E1, E2, E3};
        for (int s = 0; s < 4; s++) {
            int bits = range_bits_for(Ns[s]);
            int nb = cdiv(Ns[s], 1 << bits);
            size_t cap = (size_t)(Es[s] / nb + Es[s] / (4 * nb) + 256);
            size_t tot = cap * (size_t)nb;
            if (tot > maxPairs) maxPairs = tot;
        }
    }

    size_t uBytes = maxPairs * 4;
    if (CAP * 2 > uBytes) uBytes = CAP * 2;
    uBytes = (uBytes + 255) & ~(size_t)255;

    char* p = (char*)d_ws;
    Ws w;
    w.flag    = (int*)p;            p += 256;
    w.dis     = (float*)p;          p += maxN4 * 4;
    w.cnt     = (int*)p;            p += maxN4 * 4;
    w.rowptr  = (int*)p;            p += maxN4 * 4;
    w.gcur    = (int*)p;            p += 4 * 512 * 4;
    w.csr     = (int*)p;            p += ((maxE + 3) & ~(size_t)3) * 4;
    w.pairs   = (u32*)p;
    w.g       = (bf16*)p;           p += uBytes;
    w.act     = (bf16*)p;           p += ((CAP + 7) & ~(size_t)7) * 2;
    w.xt      = (bf16*)p;           // XTCAP bf16

    const int B = 256;

    k_detect<<<1, 256, 0, stream>>>((const u16*)x, w.flag);
    k_zero<<<8, 256, 0, stream>>>(w.gcur, 4 * 512);

    // ---- stage 1 (agg-first): aggregate x (3 feats), then @W1 -> 32
    build_csr(e0, e0 + E0, E0, N0, w.gcur + 0 * 512, w, stream);
    k_pre<3, true><<<cdiv((long long)N0 * 3, B), B, 0, stream>>>(
        x, nullptr, nullptr, w.dis, w.g, w.flag, N0 * 3);
    k_gather<3, false><<<cdiv((long long)N0 * 3, B), B, 0, stream>>>(
        w.g, w.rowptr, w.cnt, w.csr, w.dis, nullptr, w.xt, w.flag, N0 * 3);
    k_matmul_post<3, 32><<<cdiv(N0, B), B, 0, stream>>>(w.xt, W1, b1, w.act, w.flag, N0);

    // ---- stage 2 (agg-first): aggregate act1[up1] (32 feats), then @W2 -> 64
    build_csr(e1, e1 + E1, E1, N1, w.gcur + 1 * 512, w, stream);
    k_pre<32, false><<<cdiv((long long)N1 * 32, B), B, 0, stream>>>(
        nullptr, up1, w.act, w.dis, w.g, w.flag, N1 * 32);
    k_gather<32, false><<<cdiv((long long)N1 * 32, B), B, 0, stream>>>(
        w.g, w.rowptr, w.cnt, w.csr, w.dis, nullptr, w.xt, w.flag, N1 * 32);
    k_matmul_post<32, 64><<<cdiv(N1, B), B, 0, stream>>>(w.xt, W2, b2, w.act, w.flag, N1);

    // ---- stage 3 (W-first): act2[up2] @ W3 -> 32, then aggregate (32 feats)
    build_csr(e2, e2 + E2, E2, N2, w.gcur + 2 * 512, w, stream);
    k_matmul<64, 32><<<cdiv(N2, B), B, 0, stream>>>(up2, w.act, W3, w.dis, w.g, w.flag, N2);
    k_gather<32, true><<<cdiv((long long)N2 * 32, B), B, 0, stream>>>(
        w.g, w.rowptr, w.cnt, w.csr, w.dis, b3, w.act, w.flag, N2 * 32);

    // ---- stage 4 (W-first): act3[up3] @ W4 -> 3, then aggregate (3 feats)
    build_csr(e3, e3 + E3, E3, N3, w.gcur + 3 * 512, w, stream);
    k_matmul<32, 3><<<cdiv(N3, B), B, 0, stream>>>(up3, w.act, W4, w.dis, w.g, w.flag, N3);
    k_gather<3, true><<<cdiv((long long)N3 * 3, B), B, 0, stream>>>(
        w.g, w.rowptr, w.cnt, w.csr, w.dis, b4, w.act, w.flag, N3 * 3);

    // ---- final unpool
    k_gather_out<<<cdiv(N4, B), B, 0, stream>>>(w.act, up4, d_out, w.flag, N4);
}

// Round 9
// 599.484 us; speedup vs baseline: 2.8670x; 1.1939x over previous
//
#include <hip/hip_runtime.h>
#include <hip/hip_bf16.h>

typedef __hip_bfloat16 bf16;
typedef unsigned short u16;
typedef unsigned int u32;

static __device__ __forceinline__ float b2f(bf16 v) { return __bfloat162float(v); }

#define TILE 4096   // edges per partition block (LDS staging)

struct SP {
    const int* src; const int* dst;
    int E, N, bits, cap;
    int* gcur; u32* pairs;
    int* rowptr; float* dis; int* csr;
};
struct Pack {
    SP s[4];
    int poff[4];  // partition-grid start offset per stage
    int boff[4];  // build-grid start offset per stage
};

// ---------------- dtype detection ----------------
__global__ void k_detect(const u16* __restrict__ xraw, int* __restrict__ flag) {
    __shared__ int s;
    if (threadIdx.x == 0) s = 0;
    __syncthreads();
    u16 u = xraw[threadIdx.x];
    int e = (u >> 7) & 0xFF;
    if (e >= 0x8F) atomicAdd(&s, 1);
    __syncthreads();
    if (threadIdx.x == 0) flag[0] = (s > 0) ? 1 : 0;
}

// zero all 4 gcursor blocks + write rowptr sentinels
__global__ void k_init(int* __restrict__ gcur_all, Pack pk) {
    int i = blockIdx.x * blockDim.x + threadIdx.x;
    if (i < 2048) gcur_all[i] = 0;
    if (i < 4) pk.s[i].rowptr[pk.s[i].N] = pk.s[i].E;
}

// ---------------- fused pass A: all 4 stages' partitions ----------------
// LDS-staged reorder -> line-coalesced global writes.
// pairs[bucket*cap + slot] = (bucket_local_dst << 21) | src
__global__ void k_partition4(Pack pk) {
    __shared__ u32 stage[TILE];
    __shared__ u16 bkt[TILE];
    __shared__ int hist[512];
    __shared__ int lofs[512];
    __shared__ int gbase[512];
    __shared__ int lcur[512];
    __shared__ int tmp[256];

    int bid = blockIdx.x;
    int si = (bid >= pk.poff[3]) ? 3 : (bid >= pk.poff[2]) ? 2 : (bid >= pk.poff[1]) ? 1 : 0;
    const SP sp = pk.s[si];
    int lb = bid - pk.poff[si];

    int t = threadIdx.x;
    int e0 = lb * TILE;
    int n = min(TILE, sp.E - e0);
    int bits = sp.bits;

    // register-cache this thread's edges (i = t + 256*k)
    int myd[TILE / 256], mys[TILE / 256];
    int nm = 0;
    for (int i = t; i < n; i += 256) { myd[nm] = sp.dst[e0 + i]; mys[nm] = sp.src[e0 + i]; nm++; }

    for (int i = t; i < 512; i += 256) hist[i] = 0;
    __syncthreads();
    for (int k = 0; k < nm; k++)
        atomicAdd(&hist[myd[k] >> bits], 1);
    __syncthreads();

    int a0 = hist[2 * t], a1 = hist[2 * t + 1];
    int s = a0 + a1;
    tmp[t] = s; __syncthreads();
    for (int off = 1; off < 256; off <<= 1) {
        int v = (t >= off) ? tmp[t - off] : 0;
        __syncthreads();
        tmp[t] += v;
        __syncthreads();
    }
    int base = tmp[t] - s;
    lofs[2 * t] = base;
    lofs[2 * t + 1] = base + a0;
    __syncthreads();

    for (int i = t; i < 512; i += 256) {
        int h = hist[i];
        gbase[i] = h ? atomicAdd(&sp.gcur[i], h) : 0;
        lcur[i] = lofs[i];
    }
    __syncthreads();

    u32 mask = (1u << bits) - 1u;
    for (int k = 0; k < nm; k++) {
        int d = myd[k];
        int b = d >> bits;
        int pos = atomicAdd(&lcur[b], 1);
        stage[pos] = (((u32)d & mask) << 21) | (u32)mys[k];
        bkt[pos] = (u16)b;
    }
    __syncthreads();

    int cap = sp.cap;
    u32* pairs = sp.pairs;
    for (int i = t; i < n; i += 256) {
        int b = bkt[i];
        pairs[(size_t)b * cap + gbase[b] + (i - lofs[b])] = stage[i];
    }
}

// ---------------- fused pass B: all 4 stages' builds ----------------
// Each block: scan gcursor totals for its bucket base, LDS-hist its bucket,
// LDS-scan bins, write rowptr/dis coalesced, fill contiguous csr span.
__global__ void k_build4(Pack pk) {
    __shared__ int hist[2048];
    __shared__ int ofs[2048];
    __shared__ int tmp[256];
    __shared__ int bscan[512];

    int bid = blockIdx.x;
    int si = (bid >= pk.boff[3]) ? 3 : (bid >= pk.boff[2]) ? 2 : (bid >= pk.boff[1]) ? 1 : 0;
    const SP sp = pk.s[si];
    int b = bid - pk.boff[si];
    int t = threadIdx.x;
    int bits = sp.bits;
    int range = 1 << bits;

    {
        int v0 = sp.gcur[2 * t], v1 = sp.gcur[2 * t + 1];
        int s = v0 + v1;
        tmp[t] = s; __syncthreads();
        for (int off = 1; off < 256; off <<= 1) {
            int v = (t >= off) ? tmp[t - off] : 0;
            __syncthreads();
            tmp[t] += v;
            __syncthreads();
        }
        int base = tmp[t] - s;
        bscan[2 * t] = base;
        bscan[2 * t + 1] = base + v0;
        __syncthreads();
    }
    int bbase = bscan[b];
    int tot = sp.gcur[b];

    for (int i = t; i < range; i += 256) hist[i] = 0;
    __syncthreads();
    const u32* p = sp.pairs + (size_t)b * sp.cap;
    for (int i = t; i < tot; i += 256)
        atomicAdd(&hist[p[i] >> 21], 1);
    __syncthreads();

    int bpt = range >> 8;  // 1..8 bins per thread
    int lbase = t * bpt;
    int s = 0;
    for (int k = 0; k < bpt; k++) s += hist[lbase + k];
    tmp[t] = s; __syncthreads();
    for (int off = 1; off < 256; off <<= 1) {
        int v = (t >= off) ? tmp[t - off] : 0;
        __syncthreads();
        tmp[t] += v;
        __syncthreads();
    }
    int run = tmp[t] - s;
    for (int k = 0; k < bpt; k++) { ofs[lbase + k] = run; run += hist[lbase + k]; }
    __syncthreads();

    int nbase = b << bits;
    for (int i = t; i < range; i += 256) {
        int v = nbase + i;
        if (v < sp.N) {
            sp.rowptr[v] = bbase + ofs[i];
            sp.dis[v] = rsqrtf((float)(hist[i] + 1));
        }
    }
    for (int i = t; i < range; i += 256) hist[i] = ofs[i];  // reuse as cursor
    __syncthreads();
    for (int i = t; i < tot; i += 256) {
        u32 u = p[i];
        int pos = atomicAdd(&hist[u >> 21], 1);
        sp.csr[bbase + pos] = (int)(u & 0x1FFFFFu);
    }
}

// ---------------- pre-scale: g[v,f] = dis[v] * x_in[row(v), f] ----------------
template <int F, bool EXT>
__global__ void k_pre(const void* __restrict__ xin, const int* __restrict__ gidx,
                      const bf16* __restrict__ actin, const float* __restrict__ dis,
                      bf16* __restrict__ g, const int* __restrict__ flag, int total) {
    int i = blockIdx.x * blockDim.x + threadIdx.x;
    if (i >= total) return;
    int v = i / F;
    int f = i - v * F;
    float x;
    if (EXT) {
        if (flag[0]) x = ((const float*)xin)[i];
        else         x = b2f(((const bf16*)xin)[i]);
    } else {
        int row = gidx[v];
        x = b2f(actin[(size_t)row * F + f]);
    }
    g[i] = __float2bfloat16(dis[v] * x);
}

// ---------------- W-first matmul: g[v,:] = bf16(dis[v] * (act[gidx(v)] @ W)) ----------------
template <int FIN, int FOUT>
__global__ void k_matmul(const int* __restrict__ gidx, const bf16* __restrict__ actin,
                         const void* __restrict__ W, const float* __restrict__ dis,
                         bf16* __restrict__ g, const int* __restrict__ flag, int n) {
    __shared__ float Ws[FIN * FOUT];
    const int f32m = flag[0];
    for (int i = threadIdx.x; i < FIN * FOUT; i += blockDim.x)
        Ws[i] = f32m ? ((const float*)W)[i] : b2f(((const bf16*)W)[i]);
    __syncthreads();
    int v = blockIdx.x * blockDim.x + threadIdx.x;
    if (v >= n) return;
    int row = gidx[v];
    float x[FIN];
    #pragma unroll
    for (int k = 0; k < FIN; k++) x[k] = b2f(actin[(size_t)row * FIN + k]);
    float y[FOUT];
    #pragma unroll
    for (int f = 0; f < FOUT; f++) y[f] = 0.f;
    #pragma unroll
    for (int k = 0; k < FIN; k++) {
        float xk = x[k];
        #pragma unroll
        for (int f = 0; f < FOUT; f++) y[f] = fmaf(xk, Ws[k * FOUT + f], y[f]);
    }
    float dv = dis[v];
    #pragma unroll
    for (int f = 0; f < FOUT; f++)
        g[(size_t)v * FOUT + f] = __float2bfloat16(dv * y[f]);
}

// ---------------- post matmul (agg-first): act = relu(xt @ W + b) ----------------
template <int FIN, int FOUT>
__global__ void k_matmul_post(const bf16* __restrict__ xt, const void* __restrict__ W,
                              const void* __restrict__ bias, bf16* __restrict__ act,
                              const int* __restrict__ flag, int n) {
    __shared__ float Ws[FIN * FOUT];
    __shared__ float Bs[FOUT];
    const int f32m = flag[0];
    for (int i = threadIdx.x; i < FIN * FOUT; i += blockDim.x)
        Ws[i] = f32m ? ((const float*)W)[i] : b2f(((const bf16*)W)[i]);
    for (int i = threadIdx.x; i < FOUT; i += blockDim.x)
        Bs[i] = f32m ? ((const float*)bias)[i] : b2f(((const bf16*)bias)[i]);
    __syncthreads();
    int v = blockIdx.x * blockDim.x + threadIdx.x;
    if (v >= n) return;
    float x[FIN];
    #pragma unroll
    for (int k = 0; k < FIN; k++) x[k] = b2f(xt[(size_t)v * FIN + k]);
    float y[FOUT];
    #pragma unroll
    for (int f = 0; f < FOUT; f++) y[f] = Bs[f];
    #pragma unroll
    for (int k = 0; k < FIN; k++) {
        float xk = x[k];
        #pragma unroll
        for (int f = 0; f < FOUT; f++) y[f] = fmaf(xk, Ws[k * FOUT + f], y[f]);
    }
    #pragma unroll
    for (int f = 0; f < FOUT; f++)
        act[(size_t)v * FOUT + f] = __float2bfloat16(y[f] > 0.f ? y[f] : 0.f);
}

// ---------------- CSR gather, batched loads; FINALIZE: +bias, relu ----------------
template <int FOUT, bool FINALIZE>
__global__ void k_gather(const bf16* __restrict__ g, const int* __restrict__ rowptr,
                         const int* __restrict__ csr, const float* __restrict__ dis,
                         const void* __restrict__ bias, bf16* __restrict__ out,
                         const int* __restrict__ flag, int total) {
    int i = blockIdx.x * blockDim.x + threadIdx.x;
    if (i >= total) return;
    int v = i / FOUT;
    int f = i - v * FOUT;
    float s = b2f(g[i]);  // self-loop term
    int r0 = rowptr[v];
    int c = rowptr[v + 1] - r0;
    int j = 0;
    for (; j + 8 <= c; j += 8) {
        int u0 = csr[r0 + j + 0], u1 = csr[r0 + j + 1];
        int u2 = csr[r0 + j + 2], u3 = csr[r0 + j + 3];
        int u4 = csr[r0 + j + 4], u5 = csr[r0 + j + 5];
        int u6 = csr[r0 + j + 6], u7 = csr[r0 + j + 7];
        float a0 = b2f(g[(size_t)u0 * FOUT + f]);
        float a1 = b2f(g[(size_t)u1 * FOUT + f]);
        float a2 = b2f(g[(size_t)u2 * FOUT + f]);
        float a3 = b2f(g[(size_t)u3 * FOUT + f]);
        float a4 = b2f(g[(size_t)u4 * FOUT + f]);
        float a5 = b2f(g[(size_t)u5 * FOUT + f]);
        float a6 = b2f(g[(size_t)u6 * FOUT + f]);
        float a7 = b2f(g[(size_t)u7 * FOUT + f]);
        s += ((a0 + a1) + (a2 + a3)) + ((a4 + a5) + (a6 + a7));
    }
    if (j + 4 <= c) {
        int u0 = csr[r0 + j + 0], u1 = csr[r0 + j + 1];
        int u2 = csr[r0 + j + 2], u3 = csr[r0 + j + 3];
        float a0 = b2f(g[(size_t)u0 * FOUT + f]);
        float a1 = b2f(g[(size_t)u1 * FOUT + f]);
        float a2 = b2f(g[(size_t)u2 * FOUT + f]);
        float a3 = b2f(g[(size_t)u3 * FOUT + f]);
        s += (a0 + a1) + (a2 + a3);
        j += 4;
    }
    if (j + 2 <= c) {
        int u0 = csr[r0 + j + 0], u1 = csr[r0 + j + 1];
        float a0 = b2f(g[(size_t)u0 * FOUT + f]);
        float a1 = b2f(g[(size_t)u1 * FOUT + f]);
        s += a0 + a1;
        j += 2;
    }
    if (j < c)
        s += b2f(g[(size_t)csr[r0 + j] * FOUT + f]);
    float dv = dis[v];
    if (FINALIZE) {
        float bf = flag[0] ? ((const float*)bias)[f] : b2f(((const bf16*)bias)[f]);
        float val = fmaf(dv, s, bf);
        out[i] = __float2bfloat16(val > 0.f ? val : 0.f);
    } else {
        out[i] = __float2bfloat16(dv * s);
    }
}

// ---------------- final unpool gather -> out (dtype per flag) ----------------
__global__ void k_gather_out(const bf16* __restrict__ act, const int* __restrict__ idx,
                             void* __restrict__ out, const int* __restrict__ flag, int n) {
    int u = blockIdx.x * blockDim.x + threadIdx.x;
    if (u >= n) return;
    size_t r = (size_t)idx[u];
    float v0 = b2f(act[3 * r + 0]);
    float v1 = b2f(act[3 * r + 1]);
    float v2 = b2f(act[3 * r + 2]);
    if (flag[0]) {
        float* o = (float*)out;
        o[3 * (size_t)u + 0] = v0; o[3 * (size_t)u + 1] = v1; o[3 * (size_t)u + 2] = v2;
    } else {
        bf16* o = (bf16*)out;
        o[3 * (size_t)u + 0] = __float2bfloat16(v0);
        o[3 * (size_t)u + 1] = __float2bfloat16(v1);
        o[3 * (size_t)u + 2] = __float2bfloat16(v2);
    }
}

static inline int cdiv(long long a, long long b) { return (int)((a + b - 1) / b); }

static inline int range_bits_for(int N) {
    int bits = 8;
    while (cdiv(N, 1 << bits) > 512) bits++;
    return bits;
}

extern "C" void kernel_launch(void* const* d_in, const int* in_sizes, int n_in,
                              void* d_out, int out_size, void* d_ws, size_t ws_size,
                              hipStream_t stream) {
    const void* x  = d_in[0];
    const void* W1 = d_in[1]; const void* b1 = d_in[2];
    const void* W2 = d_in[3]; const void* b2 = d_in[4];
    const void* W3 = d_in[5]; const void* b3 = d_in[6];
    const void* W4 = d_in[7]; const void* b4 = d_in[8];
    const int* e0  = (const int*)d_in[9];
    const int* up1 = (const int*)d_in[10];
    const int* e1  = (const int*)d_in[11];
    const int* up2 = (const int*)d_in[12];
    const int* e2  = (const int*)d_in[13];
    const int* up3 = (const int*)d_in[14];
    const int* e3  = (const int*)d_in[15];
    const int* up4 = (const int*)d_in[16];

    const int N0 = in_sizes[0] / 3;
    const int N1 = in_sizes[10];
    const int N2 = in_sizes[12];
    const int N3 = in_sizes[14];
    const int N4 = in_sizes[16];
    const int E0 = in_sizes[9] / 2, E1 = in_sizes[11] / 2;
    const int E2 = in_sizes[13] / 2, E3 = in_sizes[15] / 2;

    int Ns[4] = {N0, N1, N2, N3};
    int Es[4] = {E0, E1, E2, E3};
    const int* srcs[4] = {e0, e1, e2, e3};
    const int* dsts[4] = {e0 + E0, e1 + E1, e2 + E2, e3 + E3};

    // buffer element counts
    size_t gmax = (size_t)N0 * 3;
    if ((size_t)N1 * 32 > gmax) gmax = (size_t)N1 * 32;
    if ((size_t)N2 * 32 > gmax) gmax = (size_t)N2 * 32;
    if ((size_t)N3 * 3  > gmax) gmax = (size_t)N3 * 3;
    size_t amax = (size_t)N0 * 32;
    if ((size_t)N1 * 64 > amax) amax = (size_t)N1 * 64;
    if ((size_t)N2 * 32 > amax) amax = (size_t)N2 * 32;
    if ((size_t)N3 * 3  > amax) amax = (size_t)N3 * 3;
    size_t xmax = (size_t)N0 * 3;
    if ((size_t)N1 * 32 > xmax) xmax = (size_t)N1 * 32;
    gmax = (gmax + 7) & ~(size_t)7;
    amax = (amax + 7) & ~(size_t)7;
    xmax = (xmax + 7) & ~(size_t)7;

    Pack pk;
    char* p = (char*)d_ws;
    int* flag = (int*)p;            p += 256;
    int* gcur_all = (int*)p;        p += 2048 * 4;

    for (int s = 0; s < 4; s++) {
        pk.s[s].src = srcs[s]; pk.s[s].dst = dsts[s];
        pk.s[s].E = Es[s]; pk.s[s].N = Ns[s];
        pk.s[s].bits = range_bits_for(Ns[s]);
        int nb = cdiv(Ns[s], 1 << pk.s[s].bits);
        pk.s[s].cap = Es[s] / nb + Es[s] / (4 * nb) + 256;
        pk.s[s].gcur = gcur_all + s * 512;
        pk.s[s].rowptr = (int*)p;   p += ((size_t)(Ns[s] + 1 + 3) & ~(size_t)3) * 4;
        pk.s[s].dis = (float*)p;    p += ((size_t)(Ns[s] + 3) & ~(size_t)3) * 4;
    }
    for (int s = 0; s < 4; s++) {
        pk.s[s].csr = (int*)p;      p += ((size_t)(Es[s] + 3) & ~(size_t)3) * 4;
    }

    // union region: pairs (build phase) aliases g|act|xt (compute phase)
    char* U = p;
    size_t pairsBytes = 0;
    for (int s = 0; s < 4; s++) {
        int nb = cdiv(Ns[s], 1 << pk.s[s].bits);
        pk.s[s].pairs = (u32*)(U + pairsBytes);
        pairsBytes += (size_t)pk.s[s].cap * nb * 4;
    }
    bf16* g   = (bf16*)U;
    bf16* act = g + gmax;
    bf16* xt  = act + amax;

    // grids
    int ptot = 0, btot = 0;
    for (int s = 0; s < 4; s++) {
        pk.poff[s] = ptot; ptot += cdiv(Es[s], TILE);
        pk.boff[s] = btot; btot += cdiv(Ns[s], 1 << pk.s[s].bits);
    }

    const int B = 256;

    k_detect<<<1, 256, 0, stream>>>((const u16*)x, flag);
    k_init<<<8, 256, 0, stream>>>(gcur_all, pk);
    k_partition4<<<ptot, B, 0, stream>>>(pk);
    k_build4<<<btot, B, 0, stream>>>(pk);

    // ---- stage 1 (agg-first): aggregate x (3 feats), then @W1 -> 32
    k_pre<3, true><<<cdiv((long long)N0 * 3, B), B, 0, stream>>>(
        x, nullptr, nullptr, pk.s[0].dis, g, flag, N0 * 3);
    k_gather<3, false><<<cdiv((long long)N0 * 3, B), B, 0, stream>>>(
        g, pk.s[0].rowptr, pk.s[0].csr, pk.s[0].dis, nullptr, xt, flag, N0 * 3);
    k_matmul_post<3, 32><<<cdiv(N0, B), B, 0, stream>>>(xt, W1, b1, act, flag, N0);

    // ---- stage 2 (agg-first): aggregate act1[up1] (32 feats), then @W2 -> 64
    k_pre<32, false><<<cdiv((long long)N1 * 32, B), B, 0, stream>>>(
        nullptr, up1, act, pk.s[1].dis, g, flag, N1 * 32);
    k_gather<32, false><<<cdiv((long long)N1 * 32, B), B, 0, stream>>>(
        g, pk.s[1].rowptr, pk.s[1].csr, pk.s[1].dis, nullptr, xt, flag, N1 * 32);
    k_matmul_post<32, 64><<<cdiv(N1, B), B, 0, stream>>>(xt, W2, b2, act, flag, N1);

    // ---- stage 3 (W-first): act2[up2] @ W3 -> 32, then aggregate (32 feats)
    k_matmul<64, 32><<<cdiv(N2, B), B, 0, stream>>>(up2, act, W3, pk.s[2].dis, g, flag, N2);
    k_gather<32, true><<<cdiv((long long)N2 * 32, B), B, 0, stream>>>(
        g, pk.s[2].rowptr, pk.s[2].csr, pk.s[2].dis, b3, act, flag, N2 * 32);

    // ---- stage 4 (W-first): act3[up3] @ W4 -> 3, then aggregate (3 feats)
    k_matmul<32, 3><<<cdiv(N3, B), B, 0, stream>>>(up3, act, W4, pk.s[3].dis, g, flag, N3);
    k_gather<3, true><<<cdiv((long long)N3 * 3, B), B, 0, stream>>>(
        g, pk.s[3].rowptr, pk.s[3].csr, pk.s[3].dis, b4, act, flag, N3 * 3);

    // ---- final unpool
    k_gather_out<<<cdiv(N4, B), B, 0, stream>>>(act, up4, d_out, flag, N4);
}

// Round 10
// 581.377 us; speedup vs baseline: 2.9563x; 1.0311x over previous
//
#include <hip/hip_runtime.h>
#include <hip/hip_bf16.h>

typedef __hip_bfloat16 bf16;
typedef unsigned short u16;
typedef unsigned int u32;

static __device__ __forceinline__ float b2f(bf16 v) { return __bfloat162float(v); }

#define TILE 2048        // edges per partition block (LDS staging)
#define EPT (TILE / 256) // edges per thread (compile-time unrolled)

struct SP {
    const int* src; const int* dst;
    int E, N, bits, cap;
    int* gcur; u32* pairs;
    int* rowptr; float* dis; int* csr;
};
struct Pack {
    SP s[4];
    int poff[4];  // partition-grid start offset per stage
    int boff[4];  // build-grid start offset per stage
};

// ---------------- dtype detection ----------------
__global__ void k_detect(const u16* __restrict__ xraw, int* __restrict__ flag) {
    __shared__ int s;
    if (threadIdx.x == 0) s = 0;
    __syncthreads();
    u16 u = xraw[threadIdx.x];
    int e = (u >> 7) & 0xFF;
    if (e >= 0x8F) atomicAdd(&s, 1);
    __syncthreads();
    if (threadIdx.x == 0) flag[0] = (s > 0) ? 1 : 0;
}

// zero all 4 gcursor blocks + write rowptr sentinels
__global__ void k_init(int* __restrict__ gcur_all, Pack pk) {
    int i = blockIdx.x * blockDim.x + threadIdx.x;
    if (i < 2048) gcur_all[i] = 0;
    if (i < 4) pk.s[i].rowptr[pk.s[i].N] = pk.s[i].E;
}

// ---------------- fused pass A: all 4 stages' partitions ----------------
// LDS-staged reorder -> line-coalesced global writes.
// pairs[bucket*cap + slot] = (bucket_local_dst << 21) | src
__global__ void k_partition4(Pack pk) {
    __shared__ u32 stage[TILE];   // 8 KB
    __shared__ u16 bkt[TILE];     // 4 KB
    __shared__ int hist[512];
    __shared__ int lofs[512];
    __shared__ int gbase[512];
    __shared__ int lcur[512];
    __shared__ int tmp[256];

    int bid = blockIdx.x;
    int si = (bid >= pk.poff[3]) ? 3 : (bid >= pk.poff[2]) ? 2 : (bid >= pk.poff[1]) ? 1 : 0;
    const SP sp = pk.s[si];
    int lb = bid - pk.poff[si];

    int t = threadIdx.x;
    int e0 = lb * TILE;
    int n = min(TILE, sp.E - e0);
    int bits = sp.bits;

    // register-cached edges; compile-time indices -> stays in VGPRs
    int myd[EPT], mys[EPT];
    #pragma unroll
    for (int k = 0; k < EPT; k++) {
        int i = t + 256 * k;
        if (i < n) { myd[k] = sp.dst[e0 + i]; mys[k] = sp.src[e0 + i]; }
        else       { myd[k] = -1; mys[k] = 0; }
    }

    for (int i = t; i < 512; i += 256) hist[i] = 0;
    __syncthreads();
    #pragma unroll
    for (int k = 0; k < EPT; k++)
        if (myd[k] >= 0) atomicAdd(&hist[myd[k] >> bits], 1);
    __syncthreads();

    int a0 = hist[2 * t], a1 = hist[2 * t + 1];
    int s = a0 + a1;
    tmp[t] = s; __syncthreads();
    for (int off = 1; off < 256; off <<= 1) {
        int v = (t >= off) ? tmp[t - off] : 0;
        __syncthreads();
        tmp[t] += v;
        __syncthreads();
    }
    int base = tmp[t] - s;
    lofs[2 * t] = base;
    lofs[2 * t + 1] = base + a0;
    __syncthreads();

    for (int i = t; i < 512; i += 256) {
        int h = hist[i];
        gbase[i] = h ? atomicAdd(&sp.gcur[i], h) : 0;
        lcur[i] = lofs[i];
    }
    __syncthreads();

    u32 mask = (1u << bits) - 1u;
    #pragma unroll
    for (int k = 0; k < EPT; k++) {
        if (myd[k] >= 0) {
            int d = myd[k];
            int b = d >> bits;
            int pos = atomicAdd(&lcur[b], 1);
            stage[pos] = (((u32)d & mask) << 21) | (u32)mys[k];
            bkt[pos] = (u16)b;
        }
    }
    __syncthreads();

    int cap = sp.cap;
    u32* pairs = sp.pairs;
    for (int i = t; i < n; i += 256) {
        int b = bkt[i];
        pairs[(size_t)b * cap + gbase[b] + (i - lofs[b])] = stage[i];
    }
}

// ---------------- fused pass B: all 4 stages' builds ----------------
__global__ void k_build4(Pack pk) {
    __shared__ int hist[2048];
    __shared__ int ofs[2048];
    __shared__ int tmp[256];
    __shared__ int bscan[512];

    int bid = blockIdx.x;
    int si = (bid >= pk.boff[3]) ? 3 : (bid >= pk.boff[2]) ? 2 : (bid >= pk.boff[1]) ? 1 : 0;
    const SP sp = pk.s[si];
    int b = bid - pk.boff[si];
    int t = threadIdx.x;
    int bits = sp.bits;
    int range = 1 << bits;

    {
        int v0 = sp.gcur[2 * t], v1 = sp.gcur[2 * t + 1];
        int s = v0 + v1;
        tmp[t] = s; __syncthreads();
        for (int off = 1; off < 256; off <<= 1) {
            int v = (t >= off) ? tmp[t - off] : 0;
            __syncthreads();
            tmp[t] += v;
            __syncthreads();
        }
        int base = tmp[t] - s;
        bscan[2 * t] = base;
        bscan[2 * t + 1] = base + v0;
        __syncthreads();
    }
    int bbase = bscan[b];
    int tot = sp.gcur[b];

    for (int i = t; i < range; i += 256) hist[i] = 0;
    __syncthreads();
    const u32* p = sp.pairs + (size_t)b * sp.cap;
    for (int i = t; i < tot; i += 256)
        atomicAdd(&hist[p[i] >> 21], 1);
    __syncthreads();

    int bpt = range >> 8;  // 1..8 bins per thread
    int lbase = t * bpt;
    int s = 0;
    for (int k = 0; k < bpt; k++) s += hist[lbase + k];
    tmp[t] = s; __syncthreads();
    for (int off = 1; off < 256; off <<= 1) {
        int v = (t >= off) ? tmp[t - off] : 0;
        __syncthreads();
        tmp[t] += v;
        __syncthreads();
    }
    int run = tmp[t] - s;
    for (int k = 0; k < bpt; k++) { ofs[lbase + k] = run; run += hist[lbase + k]; }
    __syncthreads();

    int nbase = b << bits;
    for (int i = t; i < range; i += 256) {
        int v = nbase + i;
        if (v < sp.N) {
            sp.rowptr[v] = bbase + ofs[i];
            sp.dis[v] = rsqrtf((float)(hist[i] + 1));
        }
    }
    for (int i = t; i < range; i += 256) hist[i] = ofs[i];  // reuse as cursor
    __syncthreads();
    for (int i = t; i < tot; i += 256) {
        u32 u = p[i];
        int pos = atomicAdd(&hist[u >> 21], 1);
        sp.csr[bbase + pos] = (int)(u & 0x1FFFFFu);
    }
}

// ---------------- pre-scale: g[v,f] = dis[v] * x_in[row(v), f] ----------------
template <int F, bool EXT>
__global__ void k_pre(const void* __restrict__ xin, const int* __restrict__ gidx,
                      const bf16* __restrict__ actin, const float* __restrict__ dis,
                      bf16* __restrict__ g, const int* __restrict__ flag, int total) {
    int i = blockIdx.x * blockDim.x + threadIdx.x;
    if (i >= total) return;
    int v = i / F;
    int f = i - v * F;
    float x;
    if (EXT) {
        if (flag[0]) x = ((const float*)xin)[i];
        else         x = b2f(((const bf16*)xin)[i]);
    } else {
        int row = gidx[v];
        x = b2f(actin[(size_t)row * F + f]);
    }
    g[i] = __float2bfloat16(dis[v] * x);
}

// ---------------- W-first matmul: g[v,:] = bf16(dis[v] * (act[gidx(v)] @ W)) ----------------
template <int FIN, int FOUT>
__global__ void k_matmul(const int* __restrict__ gidx, const bf16* __restrict__ actin,
                         const void* __restrict__ W, const float* __restrict__ dis,
                         bf16* __restrict__ g, const int* __restrict__ flag, int n) {
    __shared__ float Ws[FIN * FOUT];
    const int f32m = flag[0];
    for (int i = threadIdx.x; i < FIN * FOUT; i += blockDim.x)
        Ws[i] = f32m ? ((const float*)W)[i] : b2f(((const bf16*)W)[i]);
    __syncthreads();
    int v = blockIdx.x * blockDim.x + threadIdx.x;
    if (v >= n) return;
    int row = gidx[v];
    float x[FIN];
    #pragma unroll
    for (int k = 0; k < FIN; k++) x[k] = b2f(actin[(size_t)row * FIN + k]);
    float y[FOUT];
    #pragma unroll
    for (int f = 0; f < FOUT; f++) y[f] = 0.f;
    #pragma unroll
    for (int k = 0; k < FIN; k++) {
        float xk = x[k];
        #pragma unroll
        for (int f = 0; f < FOUT; f++) y[f] = fmaf(xk, Ws[k * FOUT + f], y[f]);
    }
    float dv = dis[v];
    #pragma unroll
    for (int f = 0; f < FOUT; f++)
        g[(size_t)v * FOUT + f] = __float2bfloat16(dv * y[f]);
}

// ---------------- post matmul (agg-first): act = relu(xt @ W + b) ----------------
template <int FIN, int FOUT>
__global__ void k_matmul_post(const bf16* __restrict__ xt, const void* __restrict__ W,
                              const void* __restrict__ bias, bf16* __restrict__ act,
                              const int* __restrict__ flag, int n) {
    __shared__ float Ws[FIN * FOUT];
    __shared__ float Bs[FOUT];
    const int f32m = flag[0];
    for (int i = threadIdx.x; i < FIN * FOUT; i += blockDim.x)
        Ws[i] = f32m ? ((const float*)W)[i] : b2f(((const bf16*)W)[i]);
    for (int i = threadIdx.x; i < FOUT; i += blockDim.x)
        Bs[i] = f32m ? ((const float*)bias)[i] : b2f(((const bf16*)bias)[i]);
    __syncthreads();
    int v = blockIdx.x * blockDim.x + threadIdx.x;
    if (v >= n) return;
    float x[FIN];
    #pragma unroll
    for (int k = 0; k < FIN; k++) x[k] = b2f(xt[(size_t)v * FIN + k]);
    float y[FOUT];
    #pragma unroll
    for (int f = 0; f < FOUT; f++) y[f] = Bs[f];
    #pragma unroll
    for (int k = 0; k < FIN; k++) {
        float xk = x[k];
        #pragma unroll
        for (int f = 0; f < FOUT; f++) y[f] = fmaf(xk, Ws[k * FOUT + f], y[f]);
    }
    #pragma unroll
    for (int f = 0; f < FOUT; f++)
        act[(size_t)v * FOUT + f] = __float2bfloat16(y[f] > 0.f ? y[f] : 0.f);
}

// ---------------- CSR gather, batched loads; FINALIZE: +bias, relu ----------------
template <int FOUT, bool FINALIZE>
__global__ void k_gather(const bf16* __restrict__ g, const int* __restrict__ rowptr,
                         const int* __restrict__ csr, const float* __restrict__ dis,
                         const void* __restrict__ bias, bf16* __restrict__ out,
                         const int* __restrict__ flag, int total) {
    int i = blockIdx.x * blockDim.x + threadIdx.x;
    if (i >= total) return;
    int v = i / FOUT;
    int f = i - v * FOUT;
    float s = b2f(g[i]);  // self-loop term
    int r0 = rowptr[v];
    int c = rowptr[v + 1] - r0;
    int j = 0;
    for (; j + 8 <= c; j += 8) {
        int u0 = csr[r0 + j + 0], u1 = csr[r0 + j + 1];
        int u2 = csr[r0 + j + 2], u3 = csr[r0 + j + 3];
        int u4 = csr[r0 + j + 4], u5 = csr[r0 + j + 5];
        int u6 = csr[r0 + j + 6], u7 = csr[r0 + j + 7];
        float a0 = b2f(g[(size_t)u0 * FOUT + f]);
        float a1 = b2f(g[(size_t)u1 * FOUT + f]);
        float a2 = b2f(g[(size_t)u2 * FOUT + f]);
        float a3 = b2f(g[(size_t)u3 * FOUT + f]);
        float a4 = b2f(g[(size_t)u4 * FOUT + f]);
        float a5 = b2f(g[(size_t)u5 * FOUT + f]);
        float a6 = b2f(g[(size_t)u6 * FOUT + f]);
        float a7 = b2f(g[(size_t)u7 * FOUT + f]);
        s += ((a0 + a1) + (a2 + a3)) + ((a4 + a5) + (a6 + a7));
    }
    if (j + 4 <= c) {
        int u0 = csr[r0 + j + 0], u1 = csr[r0 + j + 1];
        int u2 = csr[r0 + j + 2], u3 = csr[r0 + j + 3];
        float a0 = b2f(g[(size_t)u0 * FOUT + f]);
        float a1 = b2f(g[(size_t)u1 * FOUT + f]);
        float a2 = b2f(g[(size_t)u2 * FOUT + f]);
        float a3 = b2f(g[(size_t)u3 * FOUT + f]);
        s += (a0 + a1) + (a2 + a3);
        j += 4;
    }
    if (j + 2 <= c) {
        int u0 = csr[r0 + j + 0], u1 = csr[r0 + j + 1];
        float a0 = b2f(g[(size_t)u0 * FOUT + f]);
        float a1 = b2f(g[(size_t)u1 * FOUT + f]);
        s += a0 + a1;
        j += 2;
    }
    if (j < c)
        s += b2f(g[(size_t)csr[r0 + j] * FOUT + f]);
    float dv = dis[v];
    if (FINALIZE) {
        float bf = flag[0] ? ((const float*)bias)[f] : b2f(((const bf16*)bias)[f]);
        float val = fmaf(dv, s, bf);
        out[i] = __float2bfloat16(val > 0.f ? val : 0.f);
    } else {
        out[i] = __float2bfloat16(dv * s);
    }
}

// ---------------- final unpool gather -> out (dtype per flag) ----------------
__global__ void k_gather_out(const bf16* __restrict__ act, const int* __restrict__ idx,
                             void* __restrict__ out, const int* __restrict__ flag, int n) {
    int u = blockIdx.x * blockDim.x + threadIdx.x;
    if (u >= n) return;
    size_t r = (size_t)idx[u];
    float v0 = b2f(act[3 * r + 0]);
    float v1 = b2f(act[3 * r + 1]);
    float v2 = b2f(act[3 * r + 2]);
    if (flag[0]) {
        float* o = (float*)out;
        o[3 * (size_t)u + 0] = v0; o[3 * (size_t)u + 1] = v1; o[3 * (size_t)u + 2] = v2;
    } else {
        bf16* o = (bf16*)out;
        o[3 * (size_t)u + 0] = __float2bfloat16(v0);
        o[3 * (size_t)u + 1] = __float2bfloat16(v1);
        o[3 * (size_t)u + 2] = __float2bfloat16(v2);
    }
}

static inline int cdiv(long long a, long long b) { return (int)((a + b - 1) / b); }

static inline int range_bits_for(int N) {
    int bits = 8;
    while (cdiv(N, 1 << bits) > 512) bits++;
    return bits;
}

extern "C" void kernel_launch(void* const* d_in, const int* in_sizes, int n_in,
                              void* d_out, int out_size, void* d_ws, size_t ws_size,
                              hipStream_t stream) {
    const void* x  = d_in[0];
    const void* W1 = d_in[1]; const void* b1 = d_in[2];
    const void* W2 = d_in[3]; const void* b2 = d_in[4];
    const void* W3 = d_in[5]; const void* b3 = d_in[6];
    const void* W4 = d_in[7]; const void* b4 = d_in[8];
    const int* e0  = (const int*)d_in[9];
    const int* up1 = (const int*)d_in[10];
    const int* e1  = (const int*)d_in[11];
    const int* up2 = (const int*)d_in[12];
    const int* e2  = (const int*)d_in[13];
    const int* up3 = (const int*)d_in[14];
    const int* e3  = (const int*)d_in[15];
    const int* up4 = (const int*)d_in[16];

    const int N0 = in_sizes[0] / 3;
    const int N1 = in_sizes[10];
    const int N2 = in_sizes[12];
    const int N3 = in_sizes[14];
    const int N4 = in_sizes[16];
    const int E0 = in_sizes[9] / 2, E1 = in_sizes[11] / 2;
    const int E2 = in_sizes[13] / 2, E3 = in_sizes[15] / 2;

    int Ns[4] = {N0, N1, N2, N3};
    int Es[4] = {E0, E1, E2, E3};
    const int* srcs[4] = {e0, e1, e2, e3};
    const int* dsts[4] = {e0 + E0, e1 + E1, e2 + E2, e3 + E3};

    // buffer element counts
    size_t gmax = (size_t)N0 * 3;
    if ((size_t)N1 * 32 > gmax) gmax = (size_t)N1 * 32;
    if ((size_t)N2 * 32 > gmax) gmax = (size_t)N2 * 32;
    if ((size_t)N3 * 3  > gmax) gmax = (size_t)N3 * 3;
    size_t amax = (size_t)N0 * 32;
    if ((size_t)N1 * 64 > amax) amax = (size_t)N1 * 64;
    if ((size_t)N2 * 32 > amax) amax = (size_t)N2 * 32;
    if ((size_t)N3 * 3  > amax) amax = (size_t)N3 * 3;
    size_t xmax = (size_t)N0 * 3;
    if ((size_t)N1 * 32 > xmax) xmax = (size_t)N1 * 32;
    gmax = (gmax + 7) & ~(size_t)7;
    amax = (amax + 7) & ~(size_t)7;
    xmax = (xmax + 7) & ~(size_t)7;

    Pack pk;
    char* p = (char*)d_ws;
    int* flag = (int*)p;            p += 256;
    int* gcur_all = (int*)p;        p += 2048 * 4;

    for (int s = 0; s < 4; s++) {
        pk.s[s].src = srcs[s]; pk.s[s].dst = dsts[s];
        pk.s[s].E = Es[s]; pk.s[s].N = Ns[s];
        pk.s[s].bits = range_bits_for(Ns[s]);
        int nb = cdiv(Ns[s], 1 << pk.s[s].bits);
        pk.s[s].cap = Es[s] / nb + Es[s] / (4 * nb) + 256;
        pk.s[s].gcur = gcur_all + s * 512;
        pk.s[s].rowptr = (int*)p;   p += ((size_t)(Ns[s] + 1 + 3) & ~(size_t)3) * 4;
        pk.s[s].dis = (float*)p;    p += ((size_t)(Ns[s] + 3) & ~(size_t)3) * 4;
    }
    for (int s = 0; s < 4; s++) {
        pk.s[s].csr = (int*)p;      p += ((size_t)(Es[s] + 3) & ~(size_t)3) * 4;
    }

    // union region: pairs (build phase) aliases g|act|xt (compute phase)
    char* U = p;
    size_t pairsBytes = 0;
    for (int s = 0; s < 4; s++) {
        int nb = cdiv(Ns[s], 1 << pk.s[s].bits);
        pk.s[s].pairs = (u32*)(U + pairsBytes);
        pairsBytes += (size_t)pk.s[s].cap * nb * 4;
    }
    bf16* g   = (bf16*)U;
    bf16* act = g + gmax;
    bf16* xt  = act + amax;

    // grids
    int ptot = 0, btot = 0;
    for (int s = 0; s < 4; s++) {
        pk.poff[s] = ptot; ptot += cdiv(Es[s], TILE);
        pk.boff[s] = btot; btot += cdiv(Ns[s], 1 << pk.s[s].bits);
    }

    const int B = 256;

    k_detect<<<1, 256, 0, stream>>>((const u16*)x, flag);
    k_init<<<8, 256, 0, stream>>>(gcur_all, pk);
    k_partition4<<<ptot, B, 0, stream>>>(pk);
    k_build4<<<btot, B, 0, stream>>>(pk);

    // ---- stage 1 (agg-first): aggregate x (3 feats), then @W1 -> 32
    k_pre<3, true><<<cdiv((long long)N0 * 3, B), B, 0, stream>>>(
        x, nullptr, nullptr, pk.s[0].dis, g, flag, N0 * 3);
    k_gather<3, false><<<cdiv((long long)N0 * 3, B), B, 0, stream>>>(
        g, pk.s[0].rowptr, pk.s[0].csr, pk.s[0].dis, nullptr, xt, flag, N0 * 3);
    k_matmul_post<3, 32><<<cdiv(N0, B), B, 0, stream>>>(xt, W1, b1, act, flag, N0);

    // ---- stage 2 (agg-first): aggregate act1[up1] (32 feats), then @W2 -> 64
    k_pre<32, false><<<cdiv((long long)N1 * 32, B), B, 0, stream>>>(
        nullptr, up1, act, pk.s[1].dis, g, flag, N1 * 32);
    k_gather<32, false><<<cdiv((long long)N1 * 32, B), B, 0, stream>>>(
        g, pk.s[1].rowptr, pk.s[1].csr, pk.s[1].dis, nullptr, xt, flag, N1 * 32);
    k_matmul_post<32, 64><<<cdiv(N1, B), B, 0, stream>>>(xt, W2, b2, act, flag, N1);

    // ---- stage 3 (W-first): act2[up2] @ W3 -> 32, then aggregate (32 feats)
    k_matmul<64, 32><<<cdiv(N2, B), B, 0, stream>>>(up2, act, W3, pk.s[2].dis, g, flag, N2);
    k_gather<32, true><<<cdiv((long long)N2 * 32, B), B, 0, stream>>>(
        g, pk.s[2].rowptr, pk.s[2].csr, pk.s[2].dis, b3, act, flag, N2 * 32);

    // ---- stage 4 (W-first): act3[up3] @ W4 -> 3, then aggregate (3 feats)
    k_matmul<32, 3><<<cdiv(N3, B), B, 0, stream>>>(up3, act, W4, pk.s[3].dis, g, flag, N3);
    k_gather<3, true><<<cdiv((long long)N3 * 3, B), B, 0, stream>>>(
        g, pk.s[3].rowptr, pk.s[3].csr, pk.s[3].dis, b4, act, flag, N3 * 3);

    // ---- final unpool
    k_gather_out<<<cdiv(N4, B), B, 0, stream>>>(act, up4, d_out, flag, N4);
}

// Round 11
// 559.234 us; speedup vs baseline: 3.0733x; 1.0396x over previous
//
#include <hip/hip_runtime.h>
#include <hip/hip_bf16.h>

typedef __hip_bfloat16 bf16;
typedef unsigned short u16;
typedef unsigned char u8;
typedef unsigned int u32;

static __device__ __forceinline__ float b2f(bf16 v) { return __bfloat162float(v); }

#define TILE 4096        // edges per partition block (LDS staging)
#define RPT16(M) M(0) M(1) M(2) M(3) M(4) M(5) M(6) M(7) \
                 M(8) M(9) M(10) M(11) M(12) M(13) M(14) M(15)

struct SP {
    const int* src; const int* dst;
    int E, N, bits, cap;
    int* gcur; u32* pairs;
    int* rowptr; float* dis; int* csr;
};
struct Pack {
    SP s[4];
    int poff[4];  // partition-grid start offset per stage
    int boff[4];  // build-grid start offset per stage
};

// ---------------- dtype detection ----------------
__global__ void k_detect(const u16* __restrict__ xraw, int* __restrict__ flag) {
    __shared__ int s;
    if (threadIdx.x == 0) s = 0;
    __syncthreads();
    u16 u = xraw[threadIdx.x];
    int e = (u >> 7) & 0xFF;
    if (e >= 0x8F) atomicAdd(&s, 1);
    __syncthreads();
    if (threadIdx.x == 0) flag[0] = (s > 0) ? 1 : 0;
}

// zero all 4 gcursor blocks + write rowptr sentinels
__global__ void k_init(int* __restrict__ gcur_all, Pack pk) {
    int i = blockIdx.x * blockDim.x + threadIdx.x;
    if (i < 2048) gcur_all[i] = 0;
    if (i < 4) pk.s[i].rowptr[pk.s[i].N] = pk.s[i].E;
}

// ---------------- fused pass A: all 4 stages' partitions ----------------
// Named-scalar edge cache (no scratch), <=256 buckets, LDS-staged reorder ->
// ~84 B contiguous runs per (block,bucket) -> low write amplification.
// pairs[bucket*cap + slot] = (bucket_local_dst << 20) | src   (src < 2^20)
__global__ void k_partition4(Pack pk) {
    __shared__ u32 stage[TILE];   // 16 KB
    __shared__ u8  bkt[TILE];     //  4 KB
    __shared__ int hist[256];
    __shared__ int lofs[256];
    __shared__ int gbase[256];
    __shared__ int lcur[256];
    __shared__ int tmp[256];

    int bid = blockIdx.x;
    int si = (bid >= pk.poff[3]) ? 3 : (bid >= pk.poff[2]) ? 2 : (bid >= pk.poff[1]) ? 1 : 0;
    const SP sp = pk.s[si];
    int lb = bid - pk.poff[si];

    int t = threadIdx.x;
    int e0 = lb * TILE;
    int n = min(TILE, sp.E - e0);
    int bits = sp.bits;
    const int* dstp = sp.dst + e0;
    const int* srcp = sp.src + e0;

    // 16 named scalar pairs -> guaranteed VGPRs
#define LOADK(k) int d##k, s##k; { int i = t + 256*(k); \
    if (i < n) { d##k = dstp[i]; s##k = srcp[i]; } else { d##k = -1; s##k = 0; } }
    RPT16(LOADK)
#undef LOADK

    hist[t] = 0;
    __syncthreads();
#define HISTK(k) if (d##k >= 0) atomicAdd(&hist[d##k >> bits], 1);
    RPT16(HISTK)
#undef HISTK
    __syncthreads();

    // exclusive scan of 256 bins (1 bin per thread)
    int h = hist[t];
    tmp[t] = h; __syncthreads();
    for (int off = 1; off < 256; off <<= 1) {
        int v = (t >= off) ? tmp[t - off] : 0;
        __syncthreads();
        tmp[t] += v;
        __syncthreads();
    }
    lofs[t] = tmp[t] - h;
    gbase[t] = h ? atomicAdd(&sp.gcur[t], h) : 0;
    lcur[t] = tmp[t] - h;
    __syncthreads();

    u32 mask = (1u << bits) - 1u;
#define SCATK(k) if (d##k >= 0) { int b = d##k >> bits; \
    int pos = atomicAdd(&lcur[b], 1); \
    stage[pos] = (((u32)d##k & mask) << 20) | (u32)s##k; \
    bkt[pos] = (u8)b; }
    RPT16(SCATK)
#undef SCATK
    __syncthreads();

    int cap = sp.cap;
    u32* pairs = sp.pairs;
    for (int i = t; i < n; i += 256) {
        int b = bkt[i];
        pairs[(size_t)b * cap + gbase[b] + (i - lofs[b])] = stage[i];
    }
}

// ---------------- fused pass B: all 4 stages' builds ----------------
// Each block: scan gcursor totals for its bucket base, LDS-hist its bucket
// (<=4096 locals), LDS-scan bins, write rowptr/dis coalesced, fill csr span.
__global__ void k_build4(Pack pk) {
    __shared__ int hist[4096];   // 16 KB
    __shared__ int ofs[4096];    // 16 KB
    __shared__ int tmp[256];
    __shared__ int bscan[256];

    int bid = blockIdx.x;
    int si = (bid >= pk.boff[3]) ? 3 : (bid >= pk.boff[2]) ? 2 : (bid >= pk.boff[1]) ? 1 : 0;
    const SP sp = pk.s[si];
    int b = bid - pk.boff[si];
    int t = threadIdx.x;
    int bits = sp.bits;
    int range = 1 << bits;

    {
        int v = sp.gcur[t];
        tmp[t] = v; __syncthreads();
        for (int off = 1; off < 256; off <<= 1) {
            int w = (t >= off) ? tmp[t - off] : 0;
            __syncthreads();
            tmp[t] += w;
            __syncthreads();
        }
        bscan[t] = tmp[t] - v;
        __syncthreads();
    }
    int bbase = bscan[b];
    int tot = sp.gcur[b];

    for (int i = t; i < range; i += 256) hist[i] = 0;
    __syncthreads();
    const u32* p = sp.pairs + (size_t)b * sp.cap;
    for (int i = t; i < tot; i += 256)
        atomicAdd(&hist[p[i] >> 20], 1);
    __syncthreads();

    int bpt = range >> 8;  // 2..16 bins per thread
    int lbase = t * bpt;
    int s = 0;
    for (int k = 0; k < bpt; k++) s += hist[lbase + k];
    tmp[t] = s; __syncthreads();
    for (int off = 1; off < 256; off <<= 1) {
        int v = (t >= off) ? tmp[t - off] : 0;
        __syncthreads();
        tmp[t] += v;
        __syncthreads();
    }
    int run = tmp[t] - s;
    for (int k = 0; k < bpt; k++) { ofs[lbase + k] = run; run += hist[lbase + k]; }
    __syncthreads();

    int nbase = b << bits;
    for (int i = t; i < range; i += 256) {
        int v = nbase + i;
        if (v < sp.N) {
            sp.rowptr[v] = bbase + ofs[i];
            sp.dis[v] = rsqrtf((float)(hist[i] + 1));
        }
    }
    for (int i = t; i < range; i += 256) hist[i] = ofs[i];  // reuse as cursor
    __syncthreads();
    for (int i = t; i < tot; i += 256) {
        u32 u = p[i];
        int pos = atomicAdd(&hist[u >> 20], 1);
        sp.csr[bbase + pos] = (int)(u & 0xFFFFFu);
    }
}

// ---------------- pre-scale: g[v,f] = dis[v] * x_in[row(v), f] ----------------
template <int F, bool EXT>
__global__ void k_pre(const void* __restrict__ xin, const int* __restrict__ gidx,
                      const bf16* __restrict__ actin, const float* __restrict__ dis,
                      bf16* __restrict__ g, const int* __restrict__ flag, int total) {
    int i = blockIdx.x * blockDim.x + threadIdx.x;
    if (i >= total) return;
    int v = i / F;
    int f = i - v * F;
    float x;
    if (EXT) {
        if (flag[0]) x = ((const float*)xin)[i];
        else         x = b2f(((const bf16*)xin)[i]);
    } else {
        int row = gidx[v];
        x = b2f(actin[(size_t)row * F + f]);
    }
    g[i] = __float2bfloat16(dis[v] * x);
}

// ---------------- W-first matmul: g[v,:] = bf16(dis[v] * (act[gidx(v)] @ W)) ----------------
template <int FIN, int FOUT>
__global__ void k_matmul(const int* __restrict__ gidx, const bf16* __restrict__ actin,
                         const void* __restrict__ W, const float* __restrict__ dis,
                         bf16* __restrict__ g, const int* __restrict__ flag, int n) {
    __shared__ float Ws[FIN * FOUT];
    const int f32m = flag[0];
    for (int i = threadIdx.x; i < FIN * FOUT; i += blockDim.x)
        Ws[i] = f32m ? ((const float*)W)[i] : b2f(((const bf16*)W)[i]);
    __syncthreads();
    int v = blockIdx.x * blockDim.x + threadIdx.x;
    if (v >= n) return;
    int row = gidx[v];
    float x[FIN];
    #pragma unroll
    for (int k = 0; k < FIN; k++) x[k] = b2f(actin[(size_t)row * FIN + k]);
    float y[FOUT];
    #pragma unroll
    for (int f = 0; f < FOUT; f++) y[f] = 0.f;
    #pragma unroll
    for (int k = 0; k < FIN; k++) {
        float xk = x[k];
        #pragma unroll
        for (int f = 0; f < FOUT; f++) y[f] = fmaf(xk, Ws[k * FOUT + f], y[f]);
    }
    float dv = dis[v];
    #pragma unroll
    for (int f = 0; f < FOUT; f++)
        g[(size_t)v * FOUT + f] = __float2bfloat16(dv * y[f]);
}

// ---------------- post matmul (agg-first): act = relu(xt @ W + b) ----------------
template <int FIN, int FOUT>
__global__ void k_matmul_post(const bf16* __restrict__ xt, const void* __restrict__ W,
                              const void* __restrict__ bias, bf16* __restrict__ act,
                              const int* __restrict__ flag, int n) {
    __shared__ float Ws[FIN * FOUT];
    __shared__ float Bs[FOUT];
    const int f32m = flag[0];
    for (int i = threadIdx.x; i < FIN * FOUT; i += blockDim.x)
        Ws[i] = f32m ? ((const float*)W)[i] : b2f(((const bf16*)W)[i]);
    for (int i = threadIdx.x; i < FOUT; i += blockDim.x)
        Bs[i] = f32m ? ((const float*)bias)[i] : b2f(((const bf16*)bias)[i]);
    __syncthreads();
    int v = blockIdx.x * blockDim.x + threadIdx.x;
    if (v >= n) return;
    float x[FIN];
    #pragma unroll
    for (int k = 0; k < FIN; k++) x[k] = b2f(xt[(size_t)v * FIN + k]);
    float y[FOUT];
    #pragma unroll
    for (int f = 0; f < FOUT; f++) y[f] = Bs[f];
    #pragma unroll
    for (int k = 0; k < FIN; k++) {
        float xk = x[k];
        #pragma unroll
        for (int f = 0; f < FOUT; f++) y[f] = fmaf(xk, Ws[k * FOUT + f], y[f]);
    }
    #pragma unroll
    for (int f = 0; f < FOUT; f++)
        act[(size_t)v * FOUT + f] = __float2bfloat16(y[f] > 0.f ? y[f] : 0.f);
}

// ---------------- CSR gather, batched loads; FINALIZE: +bias, relu ----------------
template <int FOUT, bool FINALIZE>
__global__ void k_gather(const bf16* __restrict__ g, const int* __restrict__ rowptr,
                         const int* __restrict__ csr, const float* __restrict__ dis,
                         const void* __restrict__ bias, bf16* __restrict__ out,
                         const int* __restrict__ flag, int total) {
    int i = blockIdx.x * blockDim.x + threadIdx.x;
    if (i >= total) return;
    int v = i / FOUT;
    int f = i - v * FOUT;
    float s = b2f(g[i]);  // self-loop term
    int r0 = rowptr[v];
    int c = rowptr[v + 1] - r0;
    int j = 0;
    for (; j + 8 <= c; j += 8) {
        int u0 = csr[r0 + j + 0], u1 = csr[r0 + j + 1];
        int u2 = csr[r0 + j + 2], u3 = csr[r0 + j + 3];
        int u4 = csr[r0 + j + 4], u5 = csr[r0 + j + 5];
        int u6 = csr[r0 + j + 6], u7 = csr[r0 + j + 7];
        float a0 = b2f(g[(size_t)u0 * FOUT + f]);
        float a1 = b2f(g[(size_t)u1 * FOUT + f]);
        float a2 = b2f(g[(size_t)u2 * FOUT + f]);
        float a3 = b2f(g[(size_t)u3 * FOUT + f]);
        float a4 = b2f(g[(size_t)u4 * FOUT + f]);
        float a5 = b2f(g[(size_t)u5 * FOUT + f]);
        float a6 = b2f(g[(size_t)u6 * FOUT + f]);
        float a7 = b2f(g[(size_t)u7 * FOUT + f]);
        s += ((a0 + a1) + (a2 + a3)) + ((a4 + a5) + (a6 + a7));
    }
    if (j + 4 <= c) {
        int u0 = csr[r0 + j + 0], u1 = csr[r0 + j + 1];
        int u2 = csr[r0 + j + 2], u3 = csr[r0 + j + 3];
        float a0 = b2f(g[(size_t)u0 * FOUT + f]);
        float a1 = b2f(g[(size_t)u1 * FOUT + f]);
        float a2 = b2f(g[(size_t)u2 * FOUT + f]);
        float a3 = b2f(g[(size_t)u3 * FOUT + f]);
        s += (a0 + a1) + (a2 + a3);
        j += 4;
    }
    if (j + 2 <= c) {
        int u0 = csr[r0 + j + 0], u1 = csr[r0 + j + 1];
        float a0 = b2f(g[(size_t)u0 * FOUT + f]);
        float a1 = b2f(g[(size_t)u1 * FOUT + f]);
        s += a0 + a1;
        j += 2;
    }
    if (j < c)
        s += b2f(g[(size_t)csr[r0 + j] * FOUT + f]);
    float dv = dis[v];
    if (FINALIZE) {
        float bf = flag[0] ? ((const float*)bias)[f] : b2f(((const bf16*)bias)[f]);
        float val = fmaf(dv, s, bf);
        out[i] = __float2bfloat16(val > 0.f ? val : 0.f);
    } else {
        out[i] = __float2bfloat16(dv * s);
    }
}

// ---------------- final unpool gather -> out (dtype per flag) ----------------
__global__ void k_gather_out(const bf16* __restrict__ act, const int* __restrict__ idx,
                             void* __restrict__ out, const int* __restrict__ flag, int n) {
    int u = blockIdx.x * blockDim.x + threadIdx.x;
    if (u >= n) return;
    size_t r = (size_t)idx[u];
    float v0 = b2f(act[3 * r + 0]);
    float v1 = b2f(act[3 * r + 1]);
    float v2 = b2f(act[3 * r + 2]);
    if (flag[0]) {
        float* o = (float*)out;
        o[3 * (size_t)u + 0] = v0; o[3 * (size_t)u + 1] = v1; o[3 * (size_t)u + 2] = v2;
    } else {
        bf16* o = (bf16*)out;
        o[3 * (size_t)u + 0] = __float2bfloat16(v0);
        o[3 * (size_t)u + 1] = __float2bfloat16(v1);
        o[3 * (size_t)u + 2] = __float2bfloat16(v2);
    }
}

static inline int cdiv(long long a, long long b) { return (int)((a + b - 1) / b); }

// nb <= 256 buckets; local-dst fits 12 bits for N <= 1M (pack shift 20)
static inline int range_bits_for(int N) {
    int bits = 8;
    while (cdiv(N, 1 << bits) > 256) bits++;
    return bits;
}

extern "C" void kernel_launch(void* const* d_in, const int* in_sizes, int n_in,
                              void* d_out, int out_size, void* d_ws, size_t ws_size,
                              hipStream_t stream) {
    const void* x  = d_in[0];
    const void* W1 = d_in[1]; const void* b1 = d_in[2];
    const void* W2 = d_in[3]; const void* b2 = d_in[4];
    const void* W3 = d_in[5]; const void* b3 = d_in[6];
    const void* W4 = d_in[7]; const void* b4 = d_in[8];
    const int* e0  = (const int*)d_in[9];
    const int* up1 = (const int*)d_in[10];
    const int* e1  = (const int*)d_in[11];
    const int* up2 = (const int*)d_in[12];
    const int* e2  = (const int*)d_in[13];
    const int* up3 = (const int*)d_in[14];
    const int* e3  = (const int*)d_in[15];
    const int* up4 = (const int*)d_in[16];

    const int N0 = in_sizes[0] / 3;
    const int N1 = in_sizes[10];
    const int N2 = in_sizes[12];
    const int N3 = in_sizes[14];
    const int N4 = in_sizes[16];
    const int E0 = in_sizes[9] / 2, E1 = in_sizes[11] / 2;
    const int E2 = in_sizes[13] / 2, E3 = in_sizes[15] / 2;

    int Ns[4] = {N0, N1, N2, N3};
    int Es[4] = {E0, E1, E2, E3};
    const int* srcs[4] = {e0, e1, e2, e3};
    const int* dsts[4] = {e0 + E0, e1 + E1, e2 + E2, e3 + E3};

    // buffer element counts
    size_t gmax = (size_t)N0 * 3;
    if ((size_t)N1 * 32 > gmax) gmax = (size_t)N1 * 32;
    if ((size_t)N2 * 32 > gmax) gmax = (size_t)N2 * 32;
    if ((size_t)N3 * 3  > gmax) gmax = (size_t)N3 * 3;
    size_t amax = (size_t)N0 * 32;
    if ((size_t)N1 * 64 > amax) amax = (size_t)N1 * 64;
    if ((size_t)N2 * 32 > amax) amax = (size_t)N2 * 32;
    if ((size_t)N3 * 3  > amax) amax = (size_t)N3 * 3;
    size_t xmax = (size_t)N0 * 3;
    if ((size_t)N1 * 32 > xmax) xmax = (size_t)N1 * 32;
    gmax = (gmax + 7) & ~(size_t)7;
    amax = (amax + 7) & ~(size_t)7;
    xmax = (xmax + 7) & ~(size_t)7;

    Pack pk;
    char* p = (char*)d_ws;
    int* flag = (int*)p;            p += 256;
    int* gcur_all = (int*)p;        p += 2048 * 4;

    for (int s = 0; s < 4; s++) {
        pk.s[s].src = srcs[s]; pk.s[s].dst = dsts[s];
        pk.s[s].E = Es[s]; pk.s[s].N = Ns[s];
        pk.s[s].bits = range_bits_for(Ns[s]);
        int nb = cdiv(Ns[s], 1 << pk.s[s].bits);
        pk.s[s].cap = Es[s] / nb + Es[s] / (4 * nb) + 256;
        pk.s[s].gcur = gcur_all + s * 512;
        pk.s[s].rowptr = (int*)p;   p += ((size_t)(Ns[s] + 1 + 3) & ~(size_t)3) * 4;
        pk.s[s].dis = (float*)p;    p += ((size_t)(Ns[s] + 3) & ~(size_t)3) * 4;
    }
    for (int s = 0; s < 4; s++) {
        pk.s[s].csr = (int*)p;      p += ((size_t)(Es[s] + 3) & ~(size_t)3) * 4;
    }

    // union region: pairs (build phase) aliases g|act|xt (compute phase)
    char* U = p;
    size_t pairsBytes = 0;
    for (int s = 0; s < 4; s++) {
        int nb = cdiv(Ns[s], 1 << pk.s[s].bits);
        pk.s[s].pairs = (u32*)(U + pairsBytes);
        pairsBytes += (size_t)pk.s[s].cap * nb * 4;
    }
    bf16* g   = (bf16*)U;
    bf16* act = g + gmax;
    bf16* xt  = act + amax;

    // grids
    int ptot = 0, btot = 0;
    for (int s = 0; s < 4; s++) {
        pk.poff[s] = ptot; ptot += cdiv(Es[s], TILE);
        pk.boff[s] = btot; btot += cdiv(Ns[s], 1 << pk.s[s].bits);
    }

    const int B = 256;

    k_detect<<<1, 256, 0, stream>>>((const u16*)x, flag);
    k_init<<<8, 256, 0, stream>>>(gcur_all, pk);
    k_partition4<<<ptot, B, 0, stream>>>(pk);
    k_build4<<<btot, B, 0, stream>>>(pk);

    // ---- stage 1 (agg-first): aggregate x (3 feats), then @W1 -> 32
    k_pre<3, true><<<cdiv((long long)N0 * 3, B), B, 0, stream>>>(
        x, nullptr, nullptr, pk.s[0].dis, g, flag, N0 * 3);
    k_gather<3, false><<<cdiv((long long)N0 * 3, B), B, 0, stream>>>(
        g, pk.s[0].rowptr, pk.s[0].csr, pk.s[0].dis, nullptr, xt, flag, N0 * 3);
    k_matmul_post<3, 32><<<cdiv(N0, B), B, 0, stream>>>(xt, W1, b1, act, flag, N0);

    // ---- stage 2 (agg-first): aggregate act1[up1] (32 feats), then @W2 -> 64
    k_pre<32, false><<<cdiv((long long)N1 * 32, B), B, 0, stream>>>(
        nullptr, up1, act, pk.s[1].dis, g, flag, N1 * 32);
    k_gather<32, false><<<cdiv((long long)N1 * 32, B), B, 0, stream>>>(
        g, pk.s[1].rowptr, pk.s[1].csr, pk.s[1].dis, nullptr, xt, flag, N1 * 32);
    k_matmul_post<32, 64><<<cdiv(N1, B), B, 0, stream>>>(xt, W2, b2, act, flag, N1);

    // ---- stage 3 (W-first): act2[up2] @ W3 -> 32, then aggregate (32 feats)
    k_matmul<64, 32><<<cdiv(N2, B), B, 0, stream>>>(up2, act, W3, pk.s[2].dis, g, flag, N2);
    k_gather<32, true><<<cdiv((long long)N2 * 32, B), B, 0, stream>>>(
        g, pk.s[2].rowptr, pk.s[2].csr, pk.s[2].dis, b3, act, flag, N2 * 32);

    // ---- stage 4 (W-first): act3[up3] @ W4 -> 3, then aggregate (3 feats)
    k_matmul<32, 3><<<cdiv(N3, B), B, 0, stream>>>(up3, act, W4, pk.s[3].dis, g, flag, N3);
    k_gather<3, true><<<cdiv((long long)N3 * 3, B), B, 0, stream>>>(
        g, pk.s[3].rowptr, pk.s[3].csr, pk.s[3].dis, b4, act, flag, N3 * 3);

    // ---- final unpool
    k_gather_out<<<cdiv(N4, B), B, 0, stream>>>(act, up4, d_out, flag, N4);
}